// Round 1
// baseline (1447.213 us; speedup 1.0000x reference)
//
#include <hip/hip_runtime.h>
#include <stdint.h>

// Problem constants
#define BB 2
#define TT 2048
#define CC 1024
#define NH 16
#define HD 64
#define GG 32
#define NG (CC/GG)        // 32 groups per C row
#define ROWS (BB*TT)      // 4096
#define C3 (3*CC)         // 3072

// ---------------------------------------------------------------------------
// helpers
// ---------------------------------------------------------------------------
__device__ __forceinline__ int pack4f(float a, float b, float c, float d) {
  int ia = ((int)a) & 255, ib = ((int)b) & 255, ic = ((int)c) & 255, id = ((int)d) & 255;
  return ia | (ib << 8) | (ic << 16) | (id << 24);
}

__device__ __forceinline__ void unpack8(const int8_t* p, float sc, float* f) {
  int2 v = *reinterpret_cast<const int2*>(p);
  int w0 = v.x, w1 = v.y;
  f[0] = (float)((w0 << 24) >> 24) * sc;
  f[1] = (float)((w0 << 16) >> 24) * sc;
  f[2] = (float)((w0 << 8)  >> 24) * sc;
  f[3] = (float)( w0        >> 24) * sc;
  f[4] = (float)((w1 << 24) >> 24) * sc;
  f[5] = (float)((w1 << 16) >> 24) * sc;
  f[6] = (float)((w1 << 8)  >> 24) * sc;
  f[7] = (float)( w1        >> 24) * sc;
}

// ---------------------------------------------------------------------------
// group-wise symmetric int8 quantization: thread per group of 32 floats
// ---------------------------------------------------------------------------
__global__ void k_quant(const float* __restrict__ src, int8_t* __restrict__ qdst,
                        float* __restrict__ sdst, int ngroups) {
  int g = blockIdx.x * blockDim.x + threadIdx.x;
  if (g >= ngroups) return;
  const float4* p = reinterpret_cast<const float4*>(src + (size_t)g * GG);
  float vals[32];
  float amax = 0.f;
  #pragma unroll
  for (int i = 0; i < 8; ++i) {
    float4 v = p[i];
    vals[4*i+0] = v.x; vals[4*i+1] = v.y; vals[4*i+2] = v.z; vals[4*i+3] = v.w;
    amax = fmaxf(amax, fmaxf(fmaxf(fabsf(v.x), fabsf(v.y)), fmaxf(fabsf(v.z), fabsf(v.w))));
  }
  float s = fmaxf(amax / 127.0f, 1e-8f);
  float q[32];
  #pragma unroll
  for (int i = 0; i < 32; ++i) {
    float t = rintf(vals[i] / s);
    q[i] = fminf(fmaxf(t, -127.f), 127.f);
  }
  int4 w0, w1;
  w0.x = pack4f(q[0],q[1],q[2],q[3]);   w0.y = pack4f(q[4],q[5],q[6],q[7]);
  w0.z = pack4f(q[8],q[9],q[10],q[11]); w0.w = pack4f(q[12],q[13],q[14],q[15]);
  w1.x = pack4f(q[16],q[17],q[18],q[19]); w1.y = pack4f(q[20],q[21],q[22],q[23]);
  w1.z = pack4f(q[24],q[25],q[26],q[27]); w1.w = pack4f(q[28],q[29],q[30],q[31]);
  int4* qp = reinterpret_cast<int4*>(qdst + (size_t)g * GG);
  qp[0] = w0; qp[1] = w1;
  sdst[g] = s;
}

// ---------------------------------------------------------------------------
// dequant(qx)+layernorm+fake-quant -> (qh, sh). thread per group.
// ---------------------------------------------------------------------------
__global__ void k_qh(const int* __restrict__ qx, const float* __restrict__ sx,
                     const float* __restrict__ mean, const float* __restrict__ rstd,
                     const float* __restrict__ lnw,
                     int8_t* __restrict__ qh, float* __restrict__ sh) {
  int g = blockIdx.x * blockDim.x + threadIdx.x;
  if (g >= ROWS * NG) return;
  int row = g >> 5, grp = g & 31;
  float sxv = sx[g];
  float mu = mean[row], rs = rstd[row];
  const int4* qp = reinterpret_cast<const int4*>(qx + (size_t)row * CC + grp * GG);
  const float4* wp = reinterpret_cast<const float4*>(lnw + grp * GG);
  float vals[32];
  float amax = 0.f;
  #pragma unroll
  for (int i = 0; i < 8; ++i) {
    int4 qv = qp[i]; float4 wv = wp[i];
    float h0 = ((float)qv.x * sxv - mu) * rs * wv.x;
    float h1 = ((float)qv.y * sxv - mu) * rs * wv.y;
    float h2 = ((float)qv.z * sxv - mu) * rs * wv.z;
    float h3 = ((float)qv.w * sxv - mu) * rs * wv.w;
    vals[4*i+0] = h0; vals[4*i+1] = h1; vals[4*i+2] = h2; vals[4*i+3] = h3;
    amax = fmaxf(amax, fmaxf(fmaxf(fabsf(h0), fabsf(h1)), fmaxf(fabsf(h2), fabsf(h3))));
  }
  float s = fmaxf(amax / 127.0f, 1e-8f);
  float q[32];
  #pragma unroll
  for (int i = 0; i < 32; ++i) {
    float t = rintf(vals[i] / s);
    q[i] = fminf(fmaxf(t, -127.f), 127.f);
  }
  int4 w0, w1;
  w0.x = pack4f(q[0],q[1],q[2],q[3]);   w0.y = pack4f(q[4],q[5],q[6],q[7]);
  w0.z = pack4f(q[8],q[9],q[10],q[11]); w0.w = pack4f(q[12],q[13],q[14],q[15]);
  w1.x = pack4f(q[16],q[17],q[18],q[19]); w1.y = pack4f(q[20],q[21],q[22],q[23]);
  w1.z = pack4f(q[24],q[25],q[26],q[27]); w1.w = pack4f(q[28],q[29],q[30],q[31]);
  int4* op = reinterpret_cast<int4*>(qh + (size_t)row * CC + grp * GG);
  op[0] = w0; op[1] = w1;
  sh[g] = s;
}

// ---------------------------------------------------------------------------
// fp32 GEMM on dequantized int8 operands: out[m][n] = sum_k A[m][k]*B[n][k]
// K = 1024 fixed (32 groups). 64x64 tile per block, 4x4 per thread.
// ---------------------------------------------------------------------------
__global__ __launch_bounds__(256) void k_gemm(
    const int8_t* __restrict__ qa, const float* __restrict__ sa,
    const int8_t* __restrict__ qb, const float* __restrict__ sb,
    float* __restrict__ out, int N) {
  __shared__ float As[32][68];
  __shared__ float Bs[32][68];
  int tid = threadIdx.x;
  int row0 = blockIdx.y * 64, col0 = blockIdx.x * 64;
  int ty = tid >> 4, tx = tid & 15;
  int sm = tid & 63, sk = (tid >> 6) * 8;
  float acc[4][4] = {};
  for (int kg = 0; kg < 32; ++kg) {
    float fa[8], fb[8];
    int arow = row0 + sm;
    unpack8(qa + (size_t)arow * 1024 + kg * 32 + sk, sa[arow * 32 + kg], fa);
    int brow = col0 + sm;
    unpack8(qb + (size_t)brow * 1024 + kg * 32 + sk, sb[brow * 32 + kg], fb);
    __syncthreads();
    #pragma unroll
    for (int j = 0; j < 8; ++j) { As[sk + j][sm] = fa[j]; Bs[sk + j][sm] = fb[j]; }
    __syncthreads();
    #pragma unroll 8
    for (int k = 0; k < 32; ++k) {
      float4 a = *reinterpret_cast<const float4*>(&As[k][ty * 4]);
      float4 b = *reinterpret_cast<const float4*>(&Bs[k][tx * 4]);
      acc[0][0] += a.x * b.x; acc[0][1] += a.x * b.y; acc[0][2] += a.x * b.z; acc[0][3] += a.x * b.w;
      acc[1][0] += a.y * b.x; acc[1][1] += a.y * b.y; acc[1][2] += a.y * b.z; acc[1][3] += a.y * b.w;
      acc[2][0] += a.z * b.x; acc[2][1] += a.z * b.y; acc[2][2] += a.z * b.z; acc[2][3] += a.z * b.w;
      acc[3][0] += a.w * b.x; acc[3][1] += a.w * b.y; acc[3][2] += a.w * b.z; acc[3][3] += a.w * b.w;
    }
  }
  #pragma unroll
  for (int i = 0; i < 4; ++i) {
    float4 o;
    o.x = acc[i][0]; o.y = acc[i][1]; o.z = acc[i][2]; o.w = acc[i][3];
    *reinterpret_cast<float4*>(out + (size_t)(row0 + ty * 4 + i) * N + col0 + tx * 4) = o;
  }
}

// ---------------------------------------------------------------------------
// causal flash attention, fp32. grid (T/64, B*NH). 256 thr: 64 rows x 4 subs.
// ---------------------------------------------------------------------------
__global__ __launch_bounds__(256) void k_attn(const float* __restrict__ qkv,
                                              float* __restrict__ y) {
  __shared__ float Ks[64][68];
  __shared__ float Vs[64][68];
  int bh = blockIdx.y;
  int b = bh >> 4, h = bh & 15;
  int qt = blockIdx.x;
  int tid = threadIdx.x;
  int r = tid >> 2, sub = tid & 3;
  int qrow = qt * 64 + r;
  const float* qbase = qkv + ((size_t)(b * TT + qrow)) * C3 + h * HD + sub * 16;
  float qf[16];
  #pragma unroll
  for (int i = 0; i < 16; i += 4) {
    float4 v = *reinterpret_cast<const float4*>(qbase + i);
    qf[i] = v.x * 0.125f; qf[i+1] = v.y * 0.125f; qf[i+2] = v.z * 0.125f; qf[i+3] = v.w * 0.125f;
  }
  float m = -3.0e38f, l = 0.f;
  float acc[16] = {};
  for (int kt = 0; kt <= qt; ++kt) {
    {
      int jj = tid >> 2, dch = (tid & 3) * 16;
      const float* kb = qkv + ((size_t)(b * TT + kt * 64 + jj)) * C3 + CC + h * HD + dch;
      const float* vb = kb + CC;
      #pragma unroll
      for (int i = 0; i < 16; i += 4) {
        *reinterpret_cast<float4*>(&Ks[jj][dch + i]) = *reinterpret_cast<const float4*>(kb + i);
        *reinterpret_cast<float4*>(&Vs[jj][dch + i]) = *reinterpret_cast<const float4*>(vb + i);
      }
    }
    __syncthreads();
    int jmax = min(64, qrow - kt * 64 + 1);
    for (int j = 0; j < jmax; ++j) {
      float s = 0.f;
      #pragma unroll
      for (int i = 0; i < 16; i += 4) {
        float4 kv = *reinterpret_cast<const float4*>(&Ks[j][sub * 16 + i]);
        s += qf[i] * kv.x + qf[i+1] * kv.y + qf[i+2] * kv.z + qf[i+3] * kv.w;
      }
      s += __shfl_xor(s, 1, 4);
      s += __shfl_xor(s, 2, 4);
      float p;
      if (s > m) {
        float alpha = expf(m - s);
        m = s;
        l *= alpha;
        #pragma unroll
        for (int i = 0; i < 16; ++i) acc[i] *= alpha;
        p = 1.0f;
      } else {
        p = expf(s - m);
      }
      l += p;
      #pragma unroll
      for (int i = 0; i < 16; i += 4) {
        float4 vv = *reinterpret_cast<const float4*>(&Vs[j][sub * 16 + i]);
        acc[i]   += p * vv.x; acc[i+1] += p * vv.y;
        acc[i+2] += p * vv.z; acc[i+3] += p * vv.w;
      }
    }
    __syncthreads();
  }
  float inv = 1.0f / l;
  float* yb = y + ((size_t)(b * TT + qrow)) * CC + h * HD + sub * 16;
  #pragma unroll
  for (int i = 0; i < 16; i += 4) {
    float4 o;
    o.x = acc[i] * inv; o.y = acc[i+1] * inv; o.z = acc[i+2] * inv; o.w = acc[i+3] * inv;
    *reinterpret_cast<float4*>(yb + i) = o;
  }
}

// ---------------------------------------------------------------------------
// residual + stats + output quantization. block per row (1024 elems, 256 thr)
// ---------------------------------------------------------------------------
__global__ __launch_bounds__(256) void k_final(
    const float* __restrict__ x, const float* __restrict__ proj,
    float* __restrict__ out_fpx, float* __restrict__ out_qo, float* __restrict__ out_so,
    float* __restrict__ out_mean, float* __restrict__ out_rstd) {
  __shared__ float red[16];
  int row = blockIdx.x;
  int tid = threadIdx.x;
  size_t base = (size_t)row * CC + tid * 4;
  float4 xv = *reinterpret_cast<const float4*>(x + base);
  float4 pv = *reinterpret_cast<const float4*>(proj + base);
  float4 f;
  f.x = xv.x + pv.x; f.y = xv.y + pv.y; f.z = xv.z + pv.z; f.w = xv.w + pv.w;
  *reinterpret_cast<float4*>(out_fpx + base) = f;
  float sum = f.x + f.y + f.z + f.w;
  float sq  = f.x*f.x + f.y*f.y + f.z*f.z + f.w*f.w;
  #pragma unroll
  for (int off = 1; off < 64; off <<= 1) {
    sum += __shfl_xor(sum, off);
    sq  += __shfl_xor(sq, off);
  }
  int wid = tid >> 6, lane = tid & 63;
  if (lane == 0) { red[wid] = sum; red[8 + wid] = sq; }
  __syncthreads();
  if (tid == 0) {
    float s4 = red[0] + red[1] + red[2] + red[3];
    float q4 = red[8] + red[9] + red[10] + red[11];
    float mu = s4 * (1.0f / CC);
    float var = q4 * (1.0f / CC) - mu * mu;
    out_mean[row] = mu;
    out_rstd[row] = 1.0f / sqrtf(var + 1e-5f);
  }
  // group quantization: 8 threads per group of 32, 4 elems each
  float amax = fmaxf(fmaxf(fabsf(f.x), fabsf(f.y)), fmaxf(fabsf(f.z), fabsf(f.w)));
  #pragma unroll
  for (int off = 1; off < 8; off <<= 1) amax = fmaxf(amax, __shfl_xor(amax, off, 8));
  float s = fmaxf(amax / 127.0f, 1e-8f);
  int g = tid >> 3, li = tid & 7;
  if (li == 0) out_so[row * NG + g] = s;
  float4 qo;
  qo.x = fminf(fmaxf(rintf(f.x / s), -127.f), 127.f);
  qo.y = fminf(fmaxf(rintf(f.y / s), -127.f), 127.f);
  qo.z = fminf(fmaxf(rintf(f.z / s), -127.f), 127.f);
  qo.w = fminf(fmaxf(rintf(f.w / s), -127.f), 127.f);
  *reinterpret_cast<float4*>(out_qo + base) = qo;
}

// ---------------------------------------------------------------------------
extern "C" void kernel_launch(void* const* d_in, const int* in_sizes, int n_in,
                              void* d_out, int out_size, void* d_ws, size_t ws_size,
                              hipStream_t stream) {
  const float* x    = (const float*)d_in[0];
  const int*   qx   = (const int*)d_in[1];
  const float* sx   = (const float*)d_in[2];
  const float* mean = (const float*)d_in[3];
  const float* rstd = (const float*)d_in[4];
  const float* lnw  = (const float*)d_in[5];
  const float* w1   = (const float*)d_in[6];
  const float* w2   = (const float*)d_in[7];

  float* out = (float*)d_out;
  float* o_fpx  = out;
  float* o_qo   = o_fpx + (size_t)ROWS * CC;
  float* o_so   = o_qo  + (size_t)ROWS * CC;
  float* o_mean = o_so  + (size_t)ROWS * NG;
  float* o_rstd = o_mean + ROWS;

  size_t off = 0;
  char* wsb = (char*)d_ws;
  auto alloc = [&](size_t bytes) -> void* {
    void* p = wsb + off;
    off += (bytes + 255) & ~(size_t)255;
    return p;
  };
  int8_t* qh  = (int8_t*)alloc((size_t)ROWS * CC);
  int8_t* qw1 = (int8_t*)alloc((size_t)C3 * CC);
  int8_t* qw2 = (int8_t*)alloc((size_t)CC * CC);
  int8_t* qy  = (int8_t*)alloc((size_t)ROWS * CC);
  float* sh   = (float*)alloc((size_t)ROWS * NG * 4);
  float* sw1  = (float*)alloc((size_t)C3 * NG * 4);
  float* sw2  = (float*)alloc((size_t)CC * NG * 4);
  float* sy   = (float*)alloc((size_t)ROWS * NG * 4);
  float* qkv  = (float*)alloc((size_t)ROWS * C3 * 4);
  float* ybuf = (float*)alloc((size_t)ROWS * CC * 4);
  float* proj = (float*)alloc((size_t)ROWS * CC * 4);

  // 1. quantize weights
  k_quant<<<(C3 * NG + 255) / 256, 256, 0, stream>>>(w1, qw1, sw1, C3 * NG);
  k_quant<<<(CC * NG + 255) / 256, 256, 0, stream>>>(w2, qw2, sw2, CC * NG);
  // 2. LN + activation fake-quant
  k_qh<<<(ROWS * NG) / 256, 256, 0, stream>>>(qx, sx, mean, rstd, lnw, qh, sh);
  // 3. qkv = hq @ w1q^T
  k_gemm<<<dim3(C3 / 64, ROWS / 64), 256, 0, stream>>>(qh, sh, qw1, sw1, qkv, C3);
  // 4. causal SDPA
  k_attn<<<dim3(TT / 64, BB * NH), 256, 0, stream>>>(qkv, ybuf);
  // 5. y fake-quant
  k_quant<<<(ROWS * NG) / 256, 256, 0, stream>>>(ybuf, qy, sy, ROWS * NG);
  // 6. proj = yq @ w2q^T
  k_gemm<<<dim3(CC / 64, ROWS / 64), 256, 0, stream>>>(qy, sy, qw2, sw2, proj, CC);
  // 7. residual + stats + output quant
  k_final<<<ROWS, 256, 0, stream>>>(x, proj, o_fpx, o_qo, o_so, o_mean, o_rstd);
}

// Round 2
// 166.972 us; speedup vs baseline: 8.6674x; 8.6674x over previous
//
#include <hip/hip_runtime.h>
#include <stdint.h>

// Problem constants
#define BB 2
#define TT 2048
#define CC 1024
#define NH 16
#define HD 64
#define NG 32              // groups per C row (group size 32)
#define ROWS (BB*TT)       // 4096
#define C3 (3*CC)          // 3072

typedef _Float16 half_t;
typedef __attribute__((ext_vector_type(8))) _Float16 half8;
typedef __attribute__((ext_vector_type(4))) float f32x4;

#define GLDS16(g, l) __builtin_amdgcn_global_load_lds( \
    (__attribute__((address_space(1))) void*)(g), \
    (__attribute__((address_space(3))) void*)(l), 16, 0, 0)

// ---------------------------------------------------------------------------
// fake-quant fp32 -> fp16 dequantized values (group of 32 along last dim)
// ---------------------------------------------------------------------------
__global__ void k_qdq_f32(const float* __restrict__ src, half_t* __restrict__ dst,
                          int ngroups) {
  int g = blockIdx.x * blockDim.x + threadIdx.x;
  if (g >= ngroups) return;
  const float4* p = reinterpret_cast<const float4*>(src + (size_t)g * 32);
  float v[32]; float amax = 0.f;
  #pragma unroll
  for (int i = 0; i < 8; ++i) {
    float4 t = p[i];
    v[4*i] = t.x; v[4*i+1] = t.y; v[4*i+2] = t.z; v[4*i+3] = t.w;
    amax = fmaxf(amax, fmaxf(fmaxf(fabsf(t.x), fabsf(t.y)), fmaxf(fabsf(t.z), fabsf(t.w))));
  }
  float s = fmaxf(amax / 127.0f, 1e-8f);
  half_t* o = dst + (size_t)g * 32;
  #pragma unroll
  for (int c = 0; c < 4; ++c) {
    half8 ov;
    #pragma unroll
    for (int j = 0; j < 8; ++j) {
      float q = fminf(fmaxf(rintf(v[c*8+j] / s), -127.f), 127.f);
      ov[j] = (half_t)(q * s);
    }
    *reinterpret_cast<half8*>(o + c*8) = ov;
  }
}

__global__ void k_qdq_f16(const half_t* __restrict__ src, half_t* __restrict__ dst,
                          int ngroups) {
  int g = blockIdx.x * blockDim.x + threadIdx.x;
  if (g >= ngroups) return;
  const half8* p = reinterpret_cast<const half8*>(src + (size_t)g * 32);
  float v[32]; float amax = 0.f;
  #pragma unroll
  for (int i = 0; i < 4; ++i) {
    half8 t = p[i];
    #pragma unroll
    for (int j = 0; j < 8; ++j) {
      float f = (float)t[j];
      v[8*i+j] = f;
      amax = fmaxf(amax, fabsf(f));
    }
  }
  float s = fmaxf(amax / 127.0f, 1e-8f);
  half_t* o = dst + (size_t)g * 32;
  #pragma unroll
  for (int c = 0; c < 4; ++c) {
    half8 ov;
    #pragma unroll
    for (int j = 0; j < 8; ++j) {
      float q = fminf(fmaxf(rintf(v[c*8+j] / s), -127.f), 127.f);
      ov[j] = (half_t)(q * s);
    }
    *reinterpret_cast<half8*>(o + c*8) = ov;
  }
}

// ---------------------------------------------------------------------------
// dequant(qx)+layernorm+fake-quant -> fp16 h. thread per group of 32.
// ---------------------------------------------------------------------------
__global__ void k_qh(const int* __restrict__ qx, const float* __restrict__ sx,
                     const float* __restrict__ mean, const float* __restrict__ rstd,
                     const float* __restrict__ lnw, half_t* __restrict__ h16) {
  int g = blockIdx.x * blockDim.x + threadIdx.x;
  if (g >= ROWS * NG) return;
  int row = g >> 5, grp = g & 31;
  float sxv = sx[g];
  float mu = mean[row], rs = rstd[row];
  const int4* qp = reinterpret_cast<const int4*>(qx + (size_t)row * CC + grp * 32);
  const float4* wp = reinterpret_cast<const float4*>(lnw + grp * 32);
  float v[32]; float amax = 0.f;
  #pragma unroll
  for (int i = 0; i < 8; ++i) {
    int4 qv = qp[i]; float4 wv = wp[i];
    float h0 = ((float)qv.x * sxv - mu) * rs * wv.x;
    float h1 = ((float)qv.y * sxv - mu) * rs * wv.y;
    float h2 = ((float)qv.z * sxv - mu) * rs * wv.z;
    float h3 = ((float)qv.w * sxv - mu) * rs * wv.w;
    v[4*i] = h0; v[4*i+1] = h1; v[4*i+2] = h2; v[4*i+3] = h3;
    amax = fmaxf(amax, fmaxf(fmaxf(fabsf(h0), fabsf(h1)), fmaxf(fabsf(h2), fabsf(h3))));
  }
  float s = fmaxf(amax / 127.0f, 1e-8f);
  half_t* o = h16 + (size_t)row * CC + grp * 32;
  #pragma unroll
  for (int c = 0; c < 4; ++c) {
    half8 ov;
    #pragma unroll
    for (int j = 0; j < 8; ++j) {
      float q = fminf(fmaxf(rintf(v[c*8+j] / s), -127.f), 127.f);
      ov[j] = (half_t)(q * s);
    }
    *reinterpret_cast<half8*>(o + c*8) = ov;
  }
}

// ---------------------------------------------------------------------------
// fp16 MFMA GEMM: Out[m][n] = sum_k A[m][k]*B[n][k], K=1024.
// 128x128 tile, 4 waves (2x2 of 64x64), BK=32, global_load_lds staging.
// ---------------------------------------------------------------------------
template<typename TO>
__global__ __launch_bounds__(256) void k_gemm16(const half_t* __restrict__ A,
                                                const half_t* __restrict__ B,
                                                TO* __restrict__ Out, int N) {
  __shared__ __align__(16) half_t As[128*32];
  __shared__ __align__(16) half_t Bs[128*32];
  const int tid = threadIdx.x;
  const int wave = tid >> 6, lane = tid & 63;
  const int l15 = lane & 15, lg = lane >> 4;
  const int m0 = blockIdx.y * 128, n0 = blockIdx.x * 128;
  const int wm = (wave >> 1) * 64, wn = (wave & 1) * 64;
  f32x4 acc[4][4];
  #pragma unroll
  for (int i = 0; i < 4; ++i)
    #pragma unroll
    for (int j = 0; j < 4; ++j) acc[i][j] = f32x4{0.f, 0.f, 0.f, 0.f};
  const int srow = lane >> 2;        // 0..15 within segment
  const int scol = (lane & 3) * 8;   // halves
  const int seg0 = wave * 2;
  for (int k0 = 0; k0 < 1024; k0 += 32) {
    #pragma unroll
    for (int s = 0; s < 2; ++s) {
      const int seg = seg0 + s;
      GLDS16(A + (size_t)(m0 + seg*16 + srow) * 1024 + k0 + scol, As + seg*512);
      GLDS16(B + (size_t)(n0 + seg*16 + srow) * 1024 + k0 + scol, Bs + seg*512);
    }
    __syncthreads();
    half8 af[4], bf[4];
    #pragma unroll
    for (int i = 0; i < 4; ++i) {
      af[i] = *reinterpret_cast<const half8*>(As + (wm + i*16 + l15)*32 + lg*8);
      bf[i] = *reinterpret_cast<const half8*>(Bs + (wn + i*16 + l15)*32 + lg*8);
    }
    #pragma unroll
    for (int mi = 0; mi < 4; ++mi)
      #pragma unroll
      for (int ni = 0; ni < 4; ++ni)
        acc[mi][ni] = __builtin_amdgcn_mfma_f32_16x16x32_f16(af[mi], bf[ni], acc[mi][ni], 0, 0, 0);
    __syncthreads();
  }
  const int crow = m0 + wm + lg * 4;
  const int ccol = n0 + wn + l15;
  #pragma unroll
  for (int mi = 0; mi < 4; ++mi)
    #pragma unroll
    for (int ni = 0; ni < 4; ++ni)
      #pragma unroll
      for (int r = 0; r < 4; ++r)
        Out[(size_t)(crow + mi*16 + r) * N + ccol + ni*16] = (TO)acc[mi][ni][r];
}

// ---------------------------------------------------------------------------
// MFMA flash attention (swapped QK^T). grid (B*NH, T/64), 256 thr = 4 waves.
// Each wave owns 16 q-rows; KV tiles of 64 staged in LDS (V transposed).
// ---------------------------------------------------------------------------
__global__ __launch_bounds__(256) void k_attn16(const half_t* __restrict__ qkv,
                                                half_t* __restrict__ y) {
  __shared__ __align__(16) half_t Ks[64*72];
  __shared__ __align__(16) half_t Vt[64*72];
  __shared__ __align__(16) half_t Ps[4][16*72];
  const int tid = threadIdx.x;
  const int wave = tid >> 6, lane = tid & 63;
  const int l15 = lane & 15, lg = lane >> 4;
  const int bh = blockIdx.x, b = bh >> 4, h = bh & 15;
  const int qt = blockIdx.y;
  const size_t qrow = (size_t)(b * TT + qt * 64 + wave * 16 + l15);
  const half_t* qp = qkv + qrow * C3 + h * HD + lg * 8;
  const half8 qf0 = *reinterpret_cast<const half8*>(qp);
  const half8 qf1 = *reinterpret_cast<const half8*>(qp + 32);
  float m = -3.0e38f, l = 0.f;
  f32x4 yacc[4];
  #pragma unroll
  for (int n = 0; n < 4; ++n) yacc[n] = f32x4{0.f, 0.f, 0.f, 0.f};
  const int sj = tid >> 2;           // key 0..63
  const int sc = (tid & 3) * 16;     // dim chunk (halves)
  half_t* pw = &Ps[wave][0];
  for (int kt = 0; kt <= qt; ++kt) {
    const half_t* kp = qkv + (size_t)(b * TT + kt * 64 + sj) * C3 + CC + h * HD + sc;
    const half8 k0v = *reinterpret_cast<const half8*>(kp);
    const half8 k1v = *reinterpret_cast<const half8*>(kp + 8);
    const half8 v0v = *reinterpret_cast<const half8*>(kp + CC);
    const half8 v1v = *reinterpret_cast<const half8*>(kp + CC + 8);
    __syncthreads();   // previous tile's LDS reads done
    *reinterpret_cast<half8*>(Ks + sj*72 + sc) = k0v;
    *reinterpret_cast<half8*>(Ks + sj*72 + sc + 8) = k1v;
    #pragma unroll
    for (int i = 0; i < 8; ++i) {
      Vt[(sc + i) * 72 + sj] = v0v[i];
      Vt[(sc + 8 + i) * 72 + sj] = v1v[i];
    }
    __syncthreads();   // staging visible
    // S^T[key][q] = K . Q
    f32x4 sacc[4];
    #pragma unroll
    for (int kg = 0; kg < 4; ++kg) sacc[kg] = f32x4{0.f, 0.f, 0.f, 0.f};
    #pragma unroll
    for (int kg = 0; kg < 4; ++kg) {
      const half8 a0 = *reinterpret_cast<const half8*>(Ks + (kg*16 + l15)*72 + lg*8);
      const half8 a1 = *reinterpret_cast<const half8*>(Ks + (kg*16 + l15)*72 + lg*8 + 32);
      sacc[kg] = __builtin_amdgcn_mfma_f32_16x16x32_f16(a0, qf0, sacc[kg], 0, 0, 0);
      sacc[kg] = __builtin_amdgcn_mfma_f32_16x16x32_f16(a1, qf1, sacc[kg], 0, 0, 0);
    }
    // scale + causal mask + online softmax (per-lane q = wave*16 + l15)
    float sv[16]; float tm = -3.0e38f;
    const bool diag = (kt == qt);
    #pragma unroll
    for (int kg = 0; kg < 4; ++kg)
      #pragma unroll
      for (int r = 0; r < 4; ++r) {
        float s = sacc[kg][r] * 0.125f;
        if (diag && (kg*16 + lg*4 + r > wave*16 + l15)) s = -1e30f;
        sv[kg*4 + r] = s;
        tm = fmaxf(tm, s);
      }
    tm = fmaxf(tm, __shfl_xor(tm, 16));
    tm = fmaxf(tm, __shfl_xor(tm, 32));
    const float mn = fmaxf(m, tm);
    const float alpha = __expf(m - mn);
    float rs = 0.f;
    #pragma unroll
    for (int i = 0; i < 16; ++i) { sv[i] = __expf(sv[i] - mn); rs += sv[i]; }
    rs += __shfl_xor(rs, 16);
    rs += __shfl_xor(rs, 32);
    l = l * alpha + rs;
    m = mn;
    #pragma unroll
    for (int n = 0; n < 4; ++n) yacc[n] *= alpha;
    // P^T -> LDS as Ps[q][key] (wave-private)
    #pragma unroll
    for (int kg = 0; kg < 4; ++kg)
      #pragma unroll
      for (int r = 0; r < 4; ++r)
        pw[l15*72 + kg*16 + lg*4 + r] = (half_t)sv[kg*4 + r];
    const half8 pb0 = *reinterpret_cast<const half8*>(pw + l15*72 + lg*8);
    const half8 pb1 = *reinterpret_cast<const half8*>(pw + l15*72 + lg*8 + 32);
    // Y^T[dim][q] += V^T . P
    #pragma unroll
    for (int n = 0; n < 4; ++n) {
      const half8 va0 = *reinterpret_cast<const half8*>(Vt + (n*16 + l15)*72 + lg*8);
      const half8 va1 = *reinterpret_cast<const half8*>(Vt + (n*16 + l15)*72 + lg*8 + 32);
      yacc[n] = __builtin_amdgcn_mfma_f32_16x16x32_f16(va0, pb0, yacc[n], 0, 0, 0);
      yacc[n] = __builtin_amdgcn_mfma_f32_16x16x32_f16(va1, pb1, yacc[n], 0, 0, 0);
    }
  }
  const float inv = 1.0f / l;
  half_t* yp = y + qrow * CC + h * HD;
  #pragma unroll
  for (int n = 0; n < 4; ++n) {
    union { half_t h4[4]; uint64_t u; } pk;
    #pragma unroll
    for (int r = 0; r < 4; ++r) pk.h4[r] = (half_t)(yacc[n][r] * inv);
    *reinterpret_cast<uint64_t*>(yp + n*16 + lg*4) = pk.u;
  }
}

// ---------------------------------------------------------------------------
// residual + stats + output quantization. block per row (1024 elems, 256 thr)
// ---------------------------------------------------------------------------
__global__ __launch_bounds__(256) void k_final(
    const float* __restrict__ x, const float* __restrict__ proj,
    float* __restrict__ out_fpx, float* __restrict__ out_qo, float* __restrict__ out_so,
    float* __restrict__ out_mean, float* __restrict__ out_rstd) {
  __shared__ float red[16];
  int row = blockIdx.x;
  int tid = threadIdx.x;
  size_t base = (size_t)row * CC + tid * 4;
  float4 xv = *reinterpret_cast<const float4*>(x + base);
  float4 pv = *reinterpret_cast<const float4*>(proj + base);
  float4 f;
  f.x = xv.x + pv.x; f.y = xv.y + pv.y; f.z = xv.z + pv.z; f.w = xv.w + pv.w;
  *reinterpret_cast<float4*>(out_fpx + base) = f;
  float sum = f.x + f.y + f.z + f.w;
  float sq  = f.x*f.x + f.y*f.y + f.z*f.z + f.w*f.w;
  #pragma unroll
  for (int off = 1; off < 64; off <<= 1) {
    sum += __shfl_xor(sum, off);
    sq  += __shfl_xor(sq, off);
  }
  int wid = tid >> 6, lane = tid & 63;
  if (lane == 0) { red[wid] = sum; red[8 + wid] = sq; }
  __syncthreads();
  if (tid == 0) {
    float s4 = red[0] + red[1] + red[2] + red[3];
    float q4 = red[8] + red[9] + red[10] + red[11];
    float mu = s4 * (1.0f / CC);
    float var = q4 * (1.0f / CC) - mu * mu;
    out_mean[row] = mu;
    out_rstd[row] = 1.0f / sqrtf(var + 1e-5f);
  }
  float amax = fmaxf(fmaxf(fabsf(f.x), fabsf(f.y)), fmaxf(fabsf(f.z), fabsf(f.w)));
  #pragma unroll
  for (int off = 1; off < 8; off <<= 1) amax = fmaxf(amax, __shfl_xor(amax, off, 8));
  float s = fmaxf(amax / 127.0f, 1e-8f);
  int g = tid >> 3, li = tid & 7;
  if (li == 0) out_so[row * NG + g] = s;
  float4 qo;
  qo.x = fminf(fmaxf(rintf(f.x / s), -127.f), 127.f);
  qo.y = fminf(fmaxf(rintf(f.y / s), -127.f), 127.f);
  qo.z = fminf(fmaxf(rintf(f.z / s), -127.f), 127.f);
  qo.w = fminf(fmaxf(rintf(f.w / s), -127.f), 127.f);
  *reinterpret_cast<float4*>(out_qo + base) = qo;
}

// ---------------------------------------------------------------------------
extern "C" void kernel_launch(void* const* d_in, const int* in_sizes, int n_in,
                              void* d_out, int out_size, void* d_ws, size_t ws_size,
                              hipStream_t stream) {
  const float* x    = (const float*)d_in[0];
  const int*   qx   = (const int*)d_in[1];
  const float* sx   = (const float*)d_in[2];
  const float* mean = (const float*)d_in[3];
  const float* rstd = (const float*)d_in[4];
  const float* lnw  = (const float*)d_in[5];
  const float* w1   = (const float*)d_in[6];
  const float* w2   = (const float*)d_in[7];

  float* out = (float*)d_out;
  float* o_fpx  = out;
  float* o_qo   = o_fpx + (size_t)ROWS * CC;
  float* o_so   = o_qo  + (size_t)ROWS * CC;
  float* o_mean = o_so  + (size_t)ROWS * NG;
  float* o_rstd = o_mean + ROWS;

  size_t off = 0;
  char* wsb = (char*)d_ws;
  auto alloc = [&](size_t bytes) -> void* {
    void* p = wsb + off;
    off += (bytes + 255) & ~(size_t)255;
    return p;
  };
  half_t* h16   = (half_t*)alloc((size_t)ROWS * CC * 2);
  half_t* w116  = (half_t*)alloc((size_t)C3 * CC * 2);
  half_t* w216  = (half_t*)alloc((size_t)CC * CC * 2);
  half_t* y16   = (half_t*)alloc((size_t)ROWS * CC * 2);
  half_t* qkv16 = (half_t*)alloc((size_t)ROWS * C3 * 2);
  half_t* yb16  = (half_t*)alloc((size_t)ROWS * CC * 2);
  float*  proj  = (float*)alloc((size_t)ROWS * CC * 4);

  // 1. weight fake-quant -> fp16
  k_qdq_f32<<<(C3 * NG) / 256, 256, 0, stream>>>(w1, w116, C3 * NG);
  k_qdq_f32<<<(CC * NG) / 256, 256, 0, stream>>>(w2, w216, CC * NG);
  // 2. LN + activation fake-quant -> fp16
  k_qh<<<(ROWS * NG) / 256, 256, 0, stream>>>(qx, sx, mean, rstd, lnw, h16);
  // 3. qkv = h @ w1^T  (fp16 MFMA, fp16 out)
  k_gemm16<half_t><<<dim3(C3 / 128, ROWS / 128), 256, 0, stream>>>(h16, w116, qkv16, C3);
  // 4. causal SDPA (fp16 MFMA flash)
  k_attn16<<<dim3(BB * NH, TT / 64), 256, 0, stream>>>(qkv16, yb16);
  // 5. y fake-quant -> fp16
  k_qdq_f16<<<(ROWS * NG) / 256, 256, 0, stream>>>(yb16, y16, ROWS * NG);
  // 6. proj = y @ w2^T  (fp16 MFMA, fp32 out)
  k_gemm16<float><<<dim3(CC / 128, ROWS / 128), 256, 0, stream>>>(y16, w216, proj, CC);
  // 7. residual + stats + output quant
  k_final<<<ROWS, 256, 0, stream>>>(x, proj, o_fpx, o_qo, o_so, o_mean, o_rstd);
}

// Round 4
// 142.521 us; speedup vs baseline: 10.1544x; 1.1716x over previous
//
#include <hip/hip_runtime.h>
#include <stdint.h>

// Problem constants
#define BB 2
#define TT 2048
#define CC 1024
#define NH 16
#define HD 64
#define NG 32              // groups per C row (group size 32)
#define ROWS (BB*TT)       // 4096
#define C3 (3*CC)          // 3072

typedef _Float16 half_t;
typedef __attribute__((ext_vector_type(8))) _Float16 half8;
typedef __attribute__((ext_vector_type(2))) __fp16 fp16x2;
typedef __attribute__((ext_vector_type(4))) float f32x4;

#define GLDS16(g, l) __builtin_amdgcn_global_load_lds( \
    (__attribute__((address_space(1))) void*)(g), \
    (__attribute__((address_space(3))) void*)(l), 16, 0, 0)

#define LOG2E 1.44269504f
#define DEFER_THR 5.5451774f   /* 8 / log2(e) */

__device__ __forceinline__ uint32_t pk_h2(float a, float b) {
  union { fp16x2 h; uint32_t u; } cv;
  cv.h = __builtin_amdgcn_cvt_pkrtz(a, b);
  return cv.u;
}

// ---------------------------------------------------------------------------
// weight fake-quant fp32 -> fp16 dequantized values (both weights, one launch)
// ---------------------------------------------------------------------------
__global__ void k_qdq_w(const float* __restrict__ w1, const float* __restrict__ w2,
                        half_t* __restrict__ o1, half_t* __restrict__ o2) {
  int g = blockIdx.x * blockDim.x + threadIdx.x;
  const float* src; half_t* dst; int gl;
  if (g < C3 * NG) { src = w1; dst = o1; gl = g; }
  else             { src = w2; dst = o2; gl = g - C3 * NG; }
  const float4* p = reinterpret_cast<const float4*>(src + (size_t)gl * 32);
  float v[32]; float amax = 0.f;
  #pragma unroll
  for (int i = 0; i < 8; ++i) {
    float4 t = p[i];
    v[4*i] = t.x; v[4*i+1] = t.y; v[4*i+2] = t.z; v[4*i+3] = t.w;
    amax = fmaxf(amax, fmaxf(fmaxf(fabsf(t.x), fabsf(t.y)), fmaxf(fabsf(t.z), fabsf(t.w))));
  }
  float s = fmaxf(amax / 127.0f, 1e-8f);
  half_t* o = dst + (size_t)gl * 32;
  #pragma unroll
  for (int c = 0; c < 4; ++c) {
    half8 ov;
    #pragma unroll
    for (int j = 0; j < 8; ++j) {
      float q = fminf(fmaxf(rintf(v[c*8+j] / s), -127.f), 127.f);
      ov[j] = (half_t)(q * s);
    }
    *reinterpret_cast<half8*>(o + c*8) = ov;
  }
}

// ---------------------------------------------------------------------------
// dequant(qx)+layernorm+fake-quant -> fp16 h. thread per group of 32.
// ---------------------------------------------------------------------------
__global__ void k_qh(const int* __restrict__ qx, const float* __restrict__ sx,
                     const float* __restrict__ mean, const float* __restrict__ rstd,
                     const float* __restrict__ lnw, half_t* __restrict__ h16) {
  int g = blockIdx.x * blockDim.x + threadIdx.x;
  if (g >= ROWS * NG) return;
  int row = g >> 5, grp = g & 31;
  float sxv = sx[g];
  float mu = mean[row], rs = rstd[row];
  const int4* qp = reinterpret_cast<const int4*>(qx + (size_t)row * CC + grp * 32);
  const float4* wp = reinterpret_cast<const float4*>(lnw + grp * 32);
  float v[32]; float amax = 0.f;
  #pragma unroll
  for (int i = 0; i < 8; ++i) {
    int4 qv = qp[i]; float4 wv = wp[i];
    float h0 = ((float)qv.x * sxv - mu) * rs * wv.x;
    float h1 = ((float)qv.y * sxv - mu) * rs * wv.y;
    float h2 = ((float)qv.z * sxv - mu) * rs * wv.z;
    float h3 = ((float)qv.w * sxv - mu) * rs * wv.w;
    v[4*i] = h0; v[4*i+1] = h1; v[4*i+2] = h2; v[4*i+3] = h3;
    amax = fmaxf(amax, fmaxf(fmaxf(fabsf(h0), fabsf(h1)), fmaxf(fabsf(h2), fabsf(h3))));
  }
  float s = fmaxf(amax / 127.0f, 1e-8f);
  half_t* o = h16 + (size_t)row * CC + grp * 32;
  #pragma unroll
  for (int c = 0; c < 4; ++c) {
    half8 ov;
    #pragma unroll
    for (int j = 0; j < 8; ++j) {
      float q = fminf(fmaxf(rintf(v[c*8+j] / s), -127.f), 127.f);
      ov[j] = (half_t)(q * s);
    }
    *reinterpret_cast<half8*>(o + c*8) = ov;
  }
}

// ---------------------------------------------------------------------------
// fp16 MFMA GEMM: Out[m][n] = sum_k A[m][k]*B[n][k], K=1024.
// 128x128 tile, 4 waves (2x2 of 64x64), BK=32, global_load_lds staging.
// ---------------------------------------------------------------------------
template<typename TO>
__global__ __launch_bounds__(256) void k_gemm16(const half_t* __restrict__ A,
                                                const half_t* __restrict__ B,
                                                TO* __restrict__ Out, int N) {
  __shared__ __align__(16) half_t As[128*32];
  __shared__ __align__(16) half_t Bs[128*32];
  const int tid = threadIdx.x;
  const int wave = tid >> 6, lane = tid & 63;
  const int l15 = lane & 15, lg = lane >> 4;
  const int m0 = blockIdx.y * 128, n0 = blockIdx.x * 128;
  const int wm = (wave >> 1) * 64, wn = (wave & 1) * 64;
  f32x4 acc[4][4];
  #pragma unroll
  for (int i = 0; i < 4; ++i)
    #pragma unroll
    for (int j = 0; j < 4; ++j) acc[i][j] = f32x4{0.f, 0.f, 0.f, 0.f};
  const int srow = lane >> 2;        // 0..15 within segment
  const int scol = (lane & 3) * 8;   // halves
  const int seg0 = wave * 2;
  for (int k0 = 0; k0 < 1024; k0 += 32) {
    #pragma unroll
    for (int s = 0; s < 2; ++s) {
      const int seg = seg0 + s;
      GLDS16(A + (size_t)(m0 + seg*16 + srow) * 1024 + k0 + scol, As + seg*512);
      GLDS16(B + (size_t)(n0 + seg*16 + srow) * 1024 + k0 + scol, Bs + seg*512);
    }
    __syncthreads();
    half8 af[4], bf[4];
    #pragma unroll
    for (int i = 0; i < 4; ++i) {
      af[i] = *reinterpret_cast<const half8*>(As + (wm + i*16 + l15)*32 + lg*8);
      bf[i] = *reinterpret_cast<const half8*>(Bs + (wn + i*16 + l15)*32 + lg*8);
    }
    #pragma unroll
    for (int mi = 0; mi < 4; ++mi)
      #pragma unroll
      for (int ni = 0; ni < 4; ++ni)
        acc[mi][ni] = __builtin_amdgcn_mfma_f32_16x16x32_f16(af[mi], bf[ni], acc[mi][ni], 0, 0, 0);
    __syncthreads();
  }
  const int crow = m0 + wm + lg * 4;
  const int ccol = n0 + wn + l15;
  #pragma unroll
  for (int mi = 0; mi < 4; ++mi)
    #pragma unroll
    for (int ni = 0; ni < 4; ++ni)
      #pragma unroll
      for (int r = 0; r < 4; ++r)
        Out[(size_t)(crow + mi*16 + r) * N + ccol + ni*16] = (TO)acc[mi][ni][r];
}

// ---------------------------------------------------------------------------
// MFMA flash attention, paired q-tiles for uniform work.
// grid (B*NH, 16). Block j handles q-tiles {j, 31-j}: exactly 33 tile-units.
// 4 waves x 16 q-rows per tile. V^T staged with XOR-swizzled half2 writes.
// Epilogue fuses the y fake-quant (group=32 dims) and writes fp16 qdq values.
// ---------------------------------------------------------------------------
__global__ __launch_bounds__(256) void k_attn16(const half_t* __restrict__ qkv,
                                                half_t* __restrict__ y16) {
  __shared__ __align__(16) half_t Ks[64*72];
  __shared__ __align__(16) half_t Vt[64*72];   // XOR-swizzled [dim][key]
  __shared__ __align__(16) half_t Ps[4][16*72];
  const int tid = threadIdx.x;
  const int wave = tid >> 6, lane = tid & 63;
  const int l15 = lane & 15, lg = lane >> 4;
  const int bh = blockIdx.x, b = bh >> 4, h = bh & 15;
  const int j = blockIdx.y;
  const int qtA = j, qtB = 31 - j;

  // Q fragments for both tiles, prescaled by 1/sqrt(hd)=0.125 (exact in fp16)
  const size_t rowA = (size_t)(b * TT + qtA * 64 + wave * 16 + l15);
  const size_t rowB = (size_t)(b * TT + qtB * 64 + wave * 16 + l15);
  const half_t* qpA = qkv + rowA * C3 + h * HD + lg * 8;
  const half_t* qpB = qkv + rowB * C3 + h * HD + lg * 8;
  const half8 qa0 = *reinterpret_cast<const half8*>(qpA)      * (half_t)0.125f;
  const half8 qa1 = *reinterpret_cast<const half8*>(qpA + 32) * (half_t)0.125f;
  const half8 qb0 = *reinterpret_cast<const half8*>(qpB)      * (half_t)0.125f;
  const half8 qb1 = *reinterpret_cast<const half8*>(qpB + 32) * (half_t)0.125f;

  float mA = -3.0e38f, lA = 0.f, mB = -3.0e38f, lB = 0.f;
  f32x4 ya[4], yb[4];
  #pragma unroll
  for (int n = 0; n < 4; ++n) { ya[n] = f32x4{0,0,0,0}; yb[n] = f32x4{0,0,0,0}; }

  // staging maps
  const int sj = tid >> 2, sc = (tid & 3) * 16;        // K: key sj, dims sc..sc+15
  const int vk = (tid >> 3) * 2, vd0 = (tid & 7) * 8;  // V: keys vk,vk+1, dims vd0..+7
  const int vxor = ((vd0 >> 3) & 7) << 2;              // dword-index XOR (16B granular)
  half_t* pw = &Ps[wave][0];
  uint32_t* vt32 = reinterpret_cast<uint32_t*>(Vt);

  auto do_tile = [&](const half8& q0, const half8& q1, int kt, int qt,
                     float& m, float& l, f32x4* yacc) {
    f32x4 sacc[4];
    #pragma unroll
    for (int kg = 0; kg < 4; ++kg) sacc[kg] = f32x4{0,0,0,0};
    #pragma unroll
    for (int kg = 0; kg < 4; ++kg) {
      const half8 a0 = *reinterpret_cast<const half8*>(Ks + (kg*16 + l15)*72 + lg*8);
      const half8 a1 = *reinterpret_cast<const half8*>(Ks + (kg*16 + l15)*72 + lg*8 + 32);
      sacc[kg] = __builtin_amdgcn_mfma_f32_16x16x32_f16(a0, q0, sacc[kg], 0, 0, 0);
      sacc[kg] = __builtin_amdgcn_mfma_f32_16x16x32_f16(a1, q1, sacc[kg], 0, 0, 0);
    }
    float sv[16]; float tm = -3.0e38f;
    const bool diag = (kt == qt);
    #pragma unroll
    for (int kg = 0; kg < 4; ++kg)
      #pragma unroll
      for (int r = 0; r < 4; ++r) {
        float s = sacc[kg][r];
        if (diag && (kg*16 + lg*4 + r > wave*16 + l15)) s = -1e30f;
        sv[kg*4 + r] = s;
        tm = fmaxf(tm, s);
      }
    tm = fmaxf(tm, __shfl_xor(tm, 16));
    tm = fmaxf(tm, __shfl_xor(tm, 32));
    if (!__all(tm <= m + DEFER_THR)) {
      const float mn = fmaxf(m, tm);
      const float alpha = exp2f((m - mn) * LOG2E);
      l *= alpha;
      #pragma unroll
      for (int n = 0; n < 4; ++n) yacc[n] *= alpha;
      m = mn;
    }
    const float nm = -m * LOG2E;
    float rs = 0.f;
    #pragma unroll
    for (int i = 0; i < 16; ++i) { sv[i] = exp2f(fmaf(sv[i], LOG2E, nm)); rs += sv[i]; }
    rs += __shfl_xor(rs, 16);
    rs += __shfl_xor(rs, 32);
    l += rs;
    // P -> wave-private LDS (packed half2 dwords)
    uint32_t* pd = reinterpret_cast<uint32_t*>(pw) + l15*36 + lg*2;
    #pragma unroll
    for (int kg = 0; kg < 4; ++kg) {
      pd[kg*8 + 0] = pk_h2(sv[kg*4 + 0], sv[kg*4 + 1]);
      pd[kg*8 + 1] = pk_h2(sv[kg*4 + 2], sv[kg*4 + 3]);
    }
    asm volatile("" ::: "memory");
    const half8 pb0 = *reinterpret_cast<const half8*>(pw + l15*72 + lg*8);
    const half8 pb1 = *reinterpret_cast<const half8*>(pw + l15*72 + lg*8 + 32);
    #pragma unroll
    for (int n = 0; n < 4; ++n) {
      const int d = n*16 + l15;
      const int x = ((n*2 + (l15 >> 3)) & 7) << 2;
      const int dw0 = (d*36 + lg*4) ^ x;
      const int dw1 = (d*36 + 16 + lg*4) ^ x;
      const half8 va0 = *reinterpret_cast<const half8*>(vt32 + dw0);
      const half8 va1 = *reinterpret_cast<const half8*>(vt32 + dw1);
      yacc[n] = __builtin_amdgcn_mfma_f32_16x16x32_f16(va0, pb0, yacc[n], 0, 0, 0);
      yacc[n] = __builtin_amdgcn_mfma_f32_16x16x32_f16(va1, pb1, yacc[n], 0, 0, 0);
    }
  };

  const half_t* kvb = qkv + ((size_t)b * TT) * C3 + CC + h * HD;
  for (int kt = 0; kt <= qtB; ++kt) {
    const half_t* kp = kvb + (size_t)(kt*64 + sj) * C3 + sc;
    const half8 k0 = *reinterpret_cast<const half8*>(kp);
    const half8 k1 = *reinterpret_cast<const half8*>(kp + 8);
    const half_t* vp = kvb + (size_t)(kt*64 + vk) * C3 + CC + vd0;
    const half8 v0 = *reinterpret_cast<const half8*>(vp);
    const half8 v1 = *reinterpret_cast<const half8*>(vp + C3);
    __syncthreads();   // previous tile's LDS reads complete
    *reinterpret_cast<half8*>(Ks + sj*72 + sc) = k0;
    *reinterpret_cast<half8*>(Ks + sj*72 + sc + 8) = k1;
    #pragma unroll
    for (int i = 0; i < 8; ++i) {
      const int d = vd0 + i;
      vt32[(d*36 + (vk >> 1)) ^ vxor] = pk_h2((float)v0[i], (float)v1[i]);
    }
    __syncthreads();   // staging visible
    do_tile(qb0, qb1, kt, qtB, mB, lB, yb);
    if (kt <= qtA) do_tile(qa0, qa1, kt, qtA, mA, lA, ya);
  }

  // epilogue: normalize + fused group-32 fake-quant, write fp16 qdq values
  auto epi = [&](size_t row, float l, f32x4* yacc) {
    const float inv = 1.0f / l;
    float v[16];
    #pragma unroll
    for (int n = 0; n < 4; ++n)
      #pragma unroll
      for (int r = 0; r < 4; ++r) v[n*4 + r] = yacc[n][r] * inv;
    half_t* yp = y16 + row * CC + h * HD;
    #pragma unroll
    for (int g = 0; g < 2; ++g) {
      float am = 0.f;
      #pragma unroll
      for (int t = 0; t < 8; ++t) am = fmaxf(am, fabsf(v[g*8 + t]));
      am = fmaxf(am, __shfl_xor(am, 16));
      am = fmaxf(am, __shfl_xor(am, 32));
      const float s = fmaxf(am / 127.0f, 1e-8f);
      const float qi = 1.0f / s;
      #pragma unroll
      for (int nn = 0; nn < 2; ++nn) {
        const int n = g*2 + nn;
        union { half_t h4[4]; uint64_t u; } pk;
        #pragma unroll
        for (int r = 0; r < 4; ++r) {
          float q = fminf(fmaxf(rintf(v[n*4 + r] * qi), -127.f), 127.f);
          pk.h4[r] = (half_t)(q * s);
        }
        *reinterpret_cast<uint64_t*>(yp + n*16 + lg*4) = pk.u;
      }
    }
  };
  epi(rowB, lB, yb);
  epi(rowA, lA, ya);
}

// ---------------------------------------------------------------------------
// residual + stats + output quantization. block per row (1024 elems, 256 thr)
// ---------------------------------------------------------------------------
__global__ __launch_bounds__(256) void k_final(
    const float* __restrict__ x, const half_t* __restrict__ proj,
    float* __restrict__ out_fpx, float* __restrict__ out_qo, float* __restrict__ out_so,
    float* __restrict__ out_mean, float* __restrict__ out_rstd) {
  __shared__ float red[16];
  int row = blockIdx.x;
  int tid = threadIdx.x;
  size_t base = (size_t)row * CC + tid * 4;
  float4 xv = *reinterpret_cast<const float4*>(x + base);
  union { uint64_t u; half_t h[4]; } pp;
  pp.u = *reinterpret_cast<const uint64_t*>(proj + base);
  float4 f;
  f.x = xv.x + (float)pp.h[0]; f.y = xv.y + (float)pp.h[1];
  f.z = xv.z + (float)pp.h[2]; f.w = xv.w + (float)pp.h[3];
  *reinterpret_cast<float4*>(out_fpx + base) = f;
  float sum = f.x + f.y + f.z + f.w;
  float sq  = f.x*f.x + f.y*f.y + f.z*f.z + f.w*f.w;
  #pragma unroll
  for (int off = 1; off < 64; off <<= 1) {
    sum += __shfl_xor(sum, off);
    sq  += __shfl_xor(sq, off);
  }
  int wid = tid >> 6, lane = tid & 63;
  if (lane == 0) { red[wid] = sum; red[8 + wid] = sq; }
  __syncthreads();
  if (tid == 0) {
    float s4 = red[0] + red[1] + red[2] + red[3];
    float q4 = red[8] + red[9] + red[10] + red[11];
    float mu = s4 * (1.0f / CC);
    float var = q4 * (1.0f / CC) - mu * mu;
    out_mean[row] = mu;
    out_rstd[row] = 1.0f / sqrtf(var + 1e-5f);
  }
  float amax = fmaxf(fmaxf(fabsf(f.x), fabsf(f.y)), fmaxf(fabsf(f.z), fabsf(f.w)));
  #pragma unroll
  for (int off = 1; off < 8; off <<= 1) amax = fmaxf(amax, __shfl_xor(amax, off, 8));
  float s = fmaxf(amax / 127.0f, 1e-8f);
  int g = tid >> 3, li = tid & 7;
  if (li == 0) out_so[row * NG + g] = s;
  float4 qo;
  qo.x = fminf(fmaxf(rintf(f.x / s), -127.f), 127.f);
  qo.y = fminf(fmaxf(rintf(f.y / s), -127.f), 127.f);
  qo.z = fminf(fmaxf(rintf(f.z / s), -127.f), 127.f);
  qo.w = fminf(fmaxf(rintf(f.w / s), -127.f), 127.f);
  *reinterpret_cast<float4*>(out_qo + base) = qo;
}

// ---------------------------------------------------------------------------
extern "C" void kernel_launch(void* const* d_in, const int* in_sizes, int n_in,
                              void* d_out, int out_size, void* d_ws, size_t ws_size,
                              hipStream_t stream) {
  const float* x    = (const float*)d_in[0];
  const int*   qx   = (const int*)d_in[1];
  const float* sx   = (const float*)d_in[2];
  const float* mean = (const float*)d_in[3];
  const float* rstd = (const float*)d_in[4];
  const float* lnw  = (const float*)d_in[5];
  const float* w1   = (const float*)d_in[6];
  const float* w2   = (const float*)d_in[7];

  float* out = (float*)d_out;
  float* o_fpx  = out;
  float* o_qo   = o_fpx + (size_t)ROWS * CC;
  float* o_so   = o_qo  + (size_t)ROWS * CC;
  float* o_mean = o_so  + (size_t)ROWS * NG;
  float* o_rstd = o_mean + ROWS;

  size_t off = 0;
  char* wsb = (char*)d_ws;
  auto alloc = [&](size_t bytes) -> void* {
    void* p = wsb + off;
    off += (bytes + 255) & ~(size_t)255;
    return p;
  };
  half_t* h16   = (half_t*)alloc((size_t)ROWS * CC * 2);
  half_t* w116  = (half_t*)alloc((size_t)C3 * CC * 2);
  half_t* w216  = (half_t*)alloc((size_t)CC * CC * 2);
  half_t* qkv16 = (half_t*)alloc((size_t)ROWS * C3 * 2);
  half_t* y16   = (half_t*)alloc((size_t)ROWS * CC * 2);
  half_t* proj  = (half_t*)alloc((size_t)ROWS * CC * 2);

  // 1. weight fake-quant -> fp16 (both weights, one launch)
  k_qdq_w<<<(C3 * NG + CC * NG) / 256, 256, 0, stream>>>(w1, w2, w116, w216);
  // 2. LN + activation fake-quant -> fp16
  k_qh<<<(ROWS * NG) / 256, 256, 0, stream>>>(qx, sx, mean, rstd, lnw, h16);
  // 3. qkv = h @ w1^T  (fp16 MFMA, fp16 out)
  k_gemm16<half_t><<<dim3(C3 / 128, ROWS / 128), 256, 0, stream>>>(h16, w116, qkv16, C3);
  // 4. causal SDPA (fp16 MFMA flash, paired q-tiles, fused y fake-quant)
  k_attn16<<<dim3(BB * NH, 16), 256, 0, stream>>>(qkv16, y16);
  // 5. proj = y @ w2^T  (fp16 MFMA, fp16 out)
  k_gemm16<half_t><<<dim3(CC / 128, ROWS / 128), 256, 0, stream>>>(y16, w216, proj, CC);
  // 6. residual + stats + output quant
  k_final<<<ROWS, 256, 0, stream>>>(x, proj, o_fpx, o_qo, o_so, o_mean, o_rstd);
}

// Round 5
// 132.656 us; speedup vs baseline: 10.9095x; 1.0744x over previous
//
#include <hip/hip_runtime.h>
#include <stdint.h>

// Problem constants
#define BB 2
#define TT 2048
#define CC 1024
#define NH 16
#define HD 64
#define NG 32              // groups per C row (group size 32)
#define ROWS (BB*TT)       // 4096
#define C3 (3*CC)          // 3072

typedef _Float16 half_t;
typedef __attribute__((ext_vector_type(8))) _Float16 half8;
typedef __attribute__((ext_vector_type(2))) __fp16 fp16x2;
typedef __attribute__((ext_vector_type(4))) float f32x4;

#define GLDS16(g, l) __builtin_amdgcn_global_load_lds( \
    (__attribute__((address_space(1))) void*)(g), \
    (__attribute__((address_space(3))) void*)(l), 16, 0, 0)

#define LOG2E 1.44269504f
#define DEFER_THR 5.5451774f   /* 8 / log2(e) */

__device__ __forceinline__ uint32_t pk_h2(float a, float b) {
  union { fp16x2 h; uint32_t u; } cv;
  cv.h = __builtin_amdgcn_cvt_pkrtz(a, b);
  return cv.u;
}

// ---------------------------------------------------------------------------
// weight fake-quant fp32 -> fp16 dequantized values (both weights, one launch)
// ---------------------------------------------------------------------------
__global__ void k_qdq_w(const float* __restrict__ w1, const float* __restrict__ w2,
                        half_t* __restrict__ o1, half_t* __restrict__ o2) {
  int g = blockIdx.x * blockDim.x + threadIdx.x;
  const float* src; half_t* dst; int gl;
  if (g < C3 * NG) { src = w1; dst = o1; gl = g; }
  else             { src = w2; dst = o2; gl = g - C3 * NG; }
  const float4* p = reinterpret_cast<const float4*>(src + (size_t)gl * 32);
  float v[32]; float amax = 0.f;
  #pragma unroll
  for (int i = 0; i < 8; ++i) {
    float4 t = p[i];
    v[4*i] = t.x; v[4*i+1] = t.y; v[4*i+2] = t.z; v[4*i+3] = t.w;
    amax = fmaxf(amax, fmaxf(fmaxf(fabsf(t.x), fabsf(t.y)), fmaxf(fabsf(t.z), fabsf(t.w))));
  }
  float s = fmaxf(amax / 127.0f, 1e-8f);
  half_t* o = dst + (size_t)gl * 32;
  #pragma unroll
  for (int c = 0; c < 4; ++c) {
    half8 ov;
    #pragma unroll
    for (int jj = 0; jj < 8; ++jj) {
      float q = fminf(fmaxf(rintf(v[c*8+jj] / s), -127.f), 127.f);
      ov[jj] = (half_t)(q * s);
    }
    *reinterpret_cast<half8*>(o + c*8) = ov;
  }
}

// ---------------------------------------------------------------------------
// dequant(qx)+layernorm+fake-quant -> fp16 h. thread per group of 32.
// ---------------------------------------------------------------------------
__global__ void k_qh(const int* __restrict__ qx, const float* __restrict__ sx,
                     const float* __restrict__ mean, const float* __restrict__ rstd,
                     const float* __restrict__ lnw, half_t* __restrict__ h16) {
  int g = blockIdx.x * blockDim.x + threadIdx.x;
  if (g >= ROWS * NG) return;
  int row = g >> 5, grp = g & 31;
  float sxv = sx[g];
  float mu = mean[row], rs = rstd[row];
  const int4* qp = reinterpret_cast<const int4*>(qx + (size_t)row * CC + grp * 32);
  const float4* wp = reinterpret_cast<const float4*>(lnw + grp * 32);
  float v[32]; float amax = 0.f;
  #pragma unroll
  for (int i = 0; i < 8; ++i) {
    int4 qv = qp[i]; float4 wv = wp[i];
    float h0 = ((float)qv.x * sxv - mu) * rs * wv.x;
    float h1 = ((float)qv.y * sxv - mu) * rs * wv.y;
    float h2 = ((float)qv.z * sxv - mu) * rs * wv.z;
    float h3 = ((float)qv.w * sxv - mu) * rs * wv.w;
    v[4*i] = h0; v[4*i+1] = h1; v[4*i+2] = h2; v[4*i+3] = h3;
    amax = fmaxf(amax, fmaxf(fmaxf(fabsf(h0), fabsf(h1)), fmaxf(fabsf(h2), fabsf(h3))));
  }
  float s = fmaxf(amax / 127.0f, 1e-8f);
  half_t* o = h16 + (size_t)row * CC + grp * 32;
  #pragma unroll
  for (int c = 0; c < 4; ++c) {
    half8 ov;
    #pragma unroll
    for (int jj = 0; jj < 8; ++jj) {
      float q = fminf(fmaxf(rintf(v[c*8+jj] / s), -127.f), 127.f);
      ov[jj] = (half_t)(q * s);
    }
    *reinterpret_cast<half8*>(o + c*8) = ov;
  }
}

// ---------------------------------------------------------------------------
// fp16 MFMA GEMM: Out[m][n] = sum_k A[m][k]*B[n][k], K=1024.
// 128x128 tile, 4 waves (2x2 of 64x64), BK=32, global_load_lds staging.
// ---------------------------------------------------------------------------
template<typename TO>
__global__ __launch_bounds__(256) void k_gemm16(const half_t* __restrict__ A,
                                                const half_t* __restrict__ B,
                                                TO* __restrict__ Out, int N) {
  __shared__ __align__(16) half_t As[128*32];
  __shared__ __align__(16) half_t Bs[128*32];
  const int tid = threadIdx.x;
  const int wave = tid >> 6, lane = tid & 63;
  const int l15 = lane & 15, lg = lane >> 4;
  const int m0 = blockIdx.y * 128, n0 = blockIdx.x * 128;
  const int wm = (wave >> 1) * 64, wn = (wave & 1) * 64;
  f32x4 acc[4][4];
  #pragma unroll
  for (int i = 0; i < 4; ++i)
    #pragma unroll
    for (int jj = 0; jj < 4; ++jj) acc[i][jj] = f32x4{0.f, 0.f, 0.f, 0.f};
  const int srow = lane >> 2;        // 0..15 within segment
  const int scol = (lane & 3) * 8;   // halves
  const int seg0 = wave * 2;
  for (int k0 = 0; k0 < 1024; k0 += 32) {
    #pragma unroll
    for (int s = 0; s < 2; ++s) {
      const int seg = seg0 + s;
      GLDS16(A + (size_t)(m0 + seg*16 + srow) * 1024 + k0 + scol, As + seg*512);
      GLDS16(B + (size_t)(n0 + seg*16 + srow) * 1024 + k0 + scol, Bs + seg*512);
    }
    __syncthreads();
    half8 af[4], bf[4];
    #pragma unroll
    for (int i = 0; i < 4; ++i) {
      af[i] = *reinterpret_cast<const half8*>(As + (wm + i*16 + l15)*32 + lg*8);
      bf[i] = *reinterpret_cast<const half8*>(Bs + (wn + i*16 + l15)*32 + lg*8);
    }
    #pragma unroll
    for (int mi = 0; mi < 4; ++mi)
      #pragma unroll
      for (int ni = 0; ni < 4; ++ni)
        acc[mi][ni] = __builtin_amdgcn_mfma_f32_16x16x32_f16(af[mi], bf[ni], acc[mi][ni], 0, 0, 0);
    __syncthreads();
  }
  const int crow = m0 + wm + lg * 4;
  const int ccol = n0 + wn + l15;
  #pragma unroll
  for (int mi = 0; mi < 4; ++mi)
    #pragma unroll
    for (int ni = 0; ni < 4; ++ni)
      #pragma unroll
      for (int r = 0; r < 4; ++r)
        Out[(size_t)(crow + mi*16 + r) * N + ccol + ni*16] = (TO)acc[mi][ni][r];
}

// ---------------------------------------------------------------------------
// MFMA flash attention, paired q-tiles {j, 31-j} for uniform work.
// grid (B*NH, 16), 4 waves x 16 q-rows per tile.
// QK^T of both tiles issued before softmax (MFMA hides under VALU);
// V^T staged with v_perm bit-packing; row-sum l computed by MFMA ones-column;
// next-tile K/V global loads issued before compute (async-stage).
// ---------------------------------------------------------------------------
__global__ __launch_bounds__(256) void k_attn16(const half_t* __restrict__ qkv,
                                                half_t* __restrict__ y16) {
  __shared__ __align__(16) half_t Ks[64*72];
  __shared__ __align__(16) half_t Vt[64*72];   // XOR-swizzled [dim][key]
  __shared__ __align__(16) half_t PsA[4][16*72];
  __shared__ __align__(16) half_t PsB[4][16*72];
  const int tid = threadIdx.x;
  const int wave = tid >> 6, lane = tid & 63;
  const int l15 = lane & 15, lg = lane >> 4;
  const int bh = blockIdx.x, b = bh >> 4, h = bh & 15;
  const int j = blockIdx.y;
  const int qtA = j, qtB = 31 - j;

  // Q fragments for both tiles, prescaled by 1/sqrt(hd)=0.125 (exact in fp16)
  const size_t rowA = (size_t)(b * TT + qtA * 64 + wave * 16 + l15);
  const size_t rowB = (size_t)(b * TT + qtB * 64 + wave * 16 + l15);
  const half_t* qpA = qkv + rowA * C3 + h * HD + lg * 8;
  const half_t* qpB = qkv + rowB * C3 + h * HD + lg * 8;
  const half8 qa0 = *reinterpret_cast<const half8*>(qpA)      * (half_t)0.125f;
  const half8 qa1 = *reinterpret_cast<const half8*>(qpA + 32) * (half_t)0.125f;
  const half8 qb0 = *reinterpret_cast<const half8*>(qpB)      * (half_t)0.125f;
  const half8 qb1 = *reinterpret_cast<const half8*>(qpB + 32) * (half_t)0.125f;

  float mA = -3.0e38f, mB = -3.0e38f;
  f32x4 ya[4], yb[4];
  f32x4 laA = f32x4{0,0,0,0}, laB = f32x4{0,0,0,0};
  #pragma unroll
  for (int n = 0; n < 4; ++n) { ya[n] = f32x4{0,0,0,0}; yb[n] = f32x4{0,0,0,0}; }

  // staging maps
  const int sj = tid >> 2, sc = (tid & 3) * 16;        // K: key sj, dims sc..sc+15
  const int vk = (tid >> 3) * 2, vd0 = (tid & 7) * 8;  // V: keys vk,vk+1, dims vd0..+7
  const int vxor = ((vd0 >> 3) & 7) << 2;              // dword-index XOR (16B granular)
  const int kp2 = vk >> 1;
  half_t* pwA = &PsA[wave][0];
  half_t* pwB = &PsB[wave][0];
  uint32_t* vt32 = reinterpret_cast<uint32_t*>(Vt);

  // precomputed V^T read dword offsets (loop-invariant)
  int vdw0[4], vdw1[4];
  #pragma unroll
  for (int n = 0; n < 4; ++n) {
    const int d = n*16 + l15;
    const int x = ((n*2 + (l15 >> 3)) & 7) << 2;
    vdw0[n] = (d*36 + lg*4) ^ x;
    vdw1[n] = (d*36 + 16 + lg*4) ^ x;
  }

  half8 ones8;
  #pragma unroll
  for (int i = 0; i < 8; ++i) ones8[i] = (half_t)1.0f;

  // K/V prefetch registers
  half8 k0r, k1r; uint4 u0r, u1r;
  const half_t* kvb = qkv + ((size_t)b * TT) * C3 + CC + h * HD;
  auto kload = [&](int kt) {
    const half_t* kp = kvb + (size_t)(kt*64 + sj) * C3 + sc;
    k0r = *reinterpret_cast<const half8*>(kp);
    k1r = *reinterpret_cast<const half8*>(kp + 8);
    const half_t* vp = kvb + (size_t)(kt*64 + vk) * C3 + CC + vd0;
    u0r = *reinterpret_cast<const uint4*>(vp);
    u1r = *reinterpret_cast<const uint4*>(vp + C3);
  };

  auto qkt = [&](f32x4* sacc, const half8 q0, const half8 q1) {
    __builtin_amdgcn_s_setprio(1);
    #pragma unroll
    for (int kg = 0; kg < 4; ++kg) {
      const half8 a0 = *reinterpret_cast<const half8*>(Ks + (kg*16 + l15)*72 + lg*8);
      const half8 a1 = *reinterpret_cast<const half8*>(Ks + (kg*16 + l15)*72 + lg*8 + 32);
      f32x4 t = f32x4{0,0,0,0};
      t = __builtin_amdgcn_mfma_f32_16x16x32_f16(a0, q0, t, 0, 0, 0);
      t = __builtin_amdgcn_mfma_f32_16x16x32_f16(a1, q1, t, 0, 0, 0);
      sacc[kg] = t;
    }
    __builtin_amdgcn_s_setprio(0);
  };

  auto finish = [&](f32x4* sacc, bool diag, half_t* pw,
                    float& m, f32x4& lacc, f32x4* yacc) {
    float sv[16]; float tm = -3.0e38f;
    #pragma unroll
    for (int kg = 0; kg < 4; ++kg)
      #pragma unroll
      for (int r = 0; r < 4; ++r) {
        float s = sacc[kg][r];
        if (diag && (kg*16 + lg*4 + r > wave*16 + l15)) s = -1e30f;
        sv[kg*4 + r] = s;
        tm = fmaxf(tm, s);
      }
    tm = fmaxf(tm, __shfl_xor(tm, 16));
    tm = fmaxf(tm, __shfl_xor(tm, 32));
    if (!__all(tm <= m + DEFER_THR)) {
      const float mn = fmaxf(m, tm);
      const float alpha = __builtin_amdgcn_exp2f((m - mn) * LOG2E);
      #pragma unroll
      for (int n = 0; n < 4; ++n) yacc[n] *= alpha;
      lacc *= alpha;
      m = mn;
    }
    const float nm = -m * LOG2E;
    #pragma unroll
    for (int i = 0; i < 16; ++i)
      sv[i] = __builtin_amdgcn_exp2f(fmaf(sv[i], LOG2E, nm));
    // P -> wave-private LDS (packed half2 dwords)
    uint32_t* pd = reinterpret_cast<uint32_t*>(pw) + l15*36 + lg*2;
    #pragma unroll
    for (int kg = 0; kg < 4; ++kg) {
      pd[kg*8 + 0] = pk_h2(sv[kg*4 + 0], sv[kg*4 + 1]);
      pd[kg*8 + 1] = pk_h2(sv[kg*4 + 2], sv[kg*4 + 3]);
    }
    __builtin_amdgcn_sched_barrier(0);
    const half8 pb0 = *reinterpret_cast<const half8*>(pw + l15*72 + lg*8);
    const half8 pb1 = *reinterpret_cast<const half8*>(pw + l15*72 + lg*8 + 32);
    __builtin_amdgcn_s_setprio(1);
    #pragma unroll
    for (int n = 0; n < 4; ++n) {
      const half8 va0 = *reinterpret_cast<const half8*>(vt32 + vdw0[n]);
      const half8 va1 = *reinterpret_cast<const half8*>(vt32 + vdw1[n]);
      yacc[n] = __builtin_amdgcn_mfma_f32_16x16x32_f16(va0, pb0, yacc[n], 0, 0, 0);
      yacc[n] = __builtin_amdgcn_mfma_f32_16x16x32_f16(va1, pb1, yacc[n], 0, 0, 0);
    }
    lacc = __builtin_amdgcn_mfma_f32_16x16x32_f16(ones8, pb0, lacc, 0, 0, 0);
    lacc = __builtin_amdgcn_mfma_f32_16x16x32_f16(ones8, pb1, lacc, 0, 0, 0);
    __builtin_amdgcn_s_setprio(0);
  };

  kload(0);
  for (int kt = 0; kt <= qtB; ++kt) {
    __syncthreads();   // previous tile's LDS reads complete
    *reinterpret_cast<half8*>(Ks + sj*72 + sc) = k0r;
    *reinterpret_cast<half8*>(Ks + sj*72 + sc + 8) = k1r;
    {
      const uint32_t w0[4] = {u0r.x, u0r.y, u0r.z, u0r.w};
      const uint32_t w1[4] = {u1r.x, u1r.y, u1r.z, u1r.w};
      #pragma unroll
      for (int i = 0; i < 4; ++i) {
        const int d = vd0 + 2*i;
        vt32[(d*36 + kp2) ^ vxor]       = __builtin_amdgcn_perm(w1[i], w0[i], 0x05040100u);
        vt32[((d+1)*36 + kp2) ^ vxor]   = __builtin_amdgcn_perm(w1[i], w0[i], 0x07060302u);
      }
    }
    __syncthreads();   // staging visible
    if (kt < qtB) kload(kt + 1);   // prefetch next tile under compute
    const bool actA = (kt <= qtA);
    f32x4 sB[4], sA[4];
    qkt(sB, qb0, qb1);
    if (actA) qkt(sA, qa0, qa1);
    finish(sB, kt == qtB, pwB, mB, laB, yb);
    if (actA) finish(sA, kt == qtA, pwA, mA, laA, ya);
  }

  // epilogue: normalize + fused group-32 fake-quant, write fp16 qdq values
  auto epi = [&](size_t row, float l, f32x4* yacc) {
    const float inv = 1.0f / l;
    float v[16];
    #pragma unroll
    for (int n = 0; n < 4; ++n)
      #pragma unroll
      for (int r = 0; r < 4; ++r) v[n*4 + r] = yacc[n][r] * inv;
    half_t* yp = y16 + row * CC + h * HD;
    #pragma unroll
    for (int g = 0; g < 2; ++g) {
      float am = 0.f;
      #pragma unroll
      for (int t = 0; t < 8; ++t) am = fmaxf(am, fabsf(v[g*8 + t]));
      am = fmaxf(am, __shfl_xor(am, 16));
      am = fmaxf(am, __shfl_xor(am, 32));
      const float s = fmaxf(am / 127.0f, 1e-8f);
      const float qi = 1.0f / s;
      #pragma unroll
      for (int nn = 0; nn < 2; ++nn) {
        const int n = g*2 + nn;
        union { half_t h4[4]; uint64_t u; } pk;
        #pragma unroll
        for (int r = 0; r < 4; ++r) {
          float q = fminf(fmaxf(rintf(v[n*4 + r] * qi), -127.f), 127.f);
          pk.h4[r] = (half_t)(q * s);
        }
        *reinterpret_cast<uint64_t*>(yp + n*16 + lg*4) = pk.u;
      }
    }
  };
  epi(rowB, laB[0], yb);
  epi(rowA, laA[0], ya);
}

// ---------------------------------------------------------------------------
// residual + stats + output quantization. block per row (1024 elems, 256 thr)
// ---------------------------------------------------------------------------
__global__ __launch_bounds__(256) void k_final(
    const float* __restrict__ x, const half_t* __restrict__ proj,
    float* __restrict__ out_fpx, float* __restrict__ out_qo, float* __restrict__ out_so,
    float* __restrict__ out_mean, float* __restrict__ out_rstd) {
  __shared__ float red[16];
  int row = blockIdx.x;
  int tid = threadIdx.x;
  size_t base = (size_t)row * CC + tid * 4;
  float4 xv = *reinterpret_cast<const float4*>(x + base);
  union { uint64_t u; half_t h[4]; } pp;
  pp.u = *reinterpret_cast<const uint64_t*>(proj + base);
  float4 f;
  f.x = xv.x + (float)pp.h[0]; f.y = xv.y + (float)pp.h[1];
  f.z = xv.z + (float)pp.h[2]; f.w = xv.w + (float)pp.h[3];
  *reinterpret_cast<float4*>(out_fpx + base) = f;
  float sum = f.x + f.y + f.z + f.w;
  float sq  = f.x*f.x + f.y*f.y + f.z*f.z + f.w*f.w;
  #pragma unroll
  for (int off = 1; off < 64; off <<= 1) {
    sum += __shfl_xor(sum, off);
    sq  += __shfl_xor(sq, off);
  }
  int wid = tid >> 6, lane = tid & 63;
  if (lane == 0) { red[wid] = sum; red[8 + wid] = sq; }
  __syncthreads();
  if (tid == 0) {
    float s4 = red[0] + red[1] + red[2] + red[3];
    float q4 = red[8] + red[9] + red[10] + red[11];
    float mu = s4 * (1.0f / CC);
    float var = q4 * (1.0f / CC) - mu * mu;
    out_mean[row] = mu;
    out_rstd[row] = 1.0f / sqrtf(var + 1e-5f);
  }
  float amax = fmaxf(fmaxf(fabsf(f.x), fabsf(f.y)), fmaxf(fabsf(f.z), fabsf(f.w)));
  #pragma unroll
  for (int off = 1; off < 8; off <<= 1) amax = fmaxf(amax, __shfl_xor(amax, off, 8));
  float s = fmaxf(amax / 127.0f, 1e-8f);
  int g = tid >> 3, li = tid & 7;
  if (li == 0) out_so[row * NG + g] = s;
  float4 qo;
  qo.x = fminf(fmaxf(rintf(f.x / s), -127.f), 127.f);
  qo.y = fminf(fmaxf(rintf(f.y / s), -127.f), 127.f);
  qo.z = fminf(fmaxf(rintf(f.z / s), -127.f), 127.f);
  qo.w = fminf(fmaxf(rintf(f.w / s), -127.f), 127.f);
  *reinterpret_cast<float4*>(out_qo + base) = qo;
}

// ---------------------------------------------------------------------------
extern "C" void kernel_launch(void* const* d_in, const int* in_sizes, int n_in,
                              void* d_out, int out_size, void* d_ws, size_t ws_size,
                              hipStream_t stream) {
  const float* x    = (const float*)d_in[0];
  const int*   qx   = (const int*)d_in[1];
  const float* sx   = (const float*)d_in[2];
  const float* mean = (const float*)d_in[3];
  const float* rstd = (const float*)d_in[4];
  const float* lnw  = (const float*)d_in[5];
  const float* w1   = (const float*)d_in[6];
  const float* w2   = (const float*)d_in[7];

  float* out = (float*)d_out;
  float* o_fpx  = out;
  float* o_qo   = o_fpx + (size_t)ROWS * CC;
  float* o_so   = o_qo  + (size_t)ROWS * CC;
  float* o_mean = o_so  + (size_t)ROWS * NG;
  float* o_rstd = o_mean + ROWS;

  size_t off = 0;
  char* wsb = (char*)d_ws;
  auto alloc = [&](size_t bytes) -> void* {
    void* p = wsb + off;
    off += (bytes + 255) & ~(size_t)255;
    return p;
  };
  half_t* h16   = (half_t*)alloc((size_t)ROWS * CC * 2);
  half_t* w116  = (half_t*)alloc((size_t)C3 * CC * 2);
  half_t* w216  = (half_t*)alloc((size_t)CC * CC * 2);
  half_t* qkv16 = (half_t*)alloc((size_t)ROWS * C3 * 2);
  half_t* y16   = (half_t*)alloc((size_t)ROWS * CC * 2);
  half_t* proj  = (half_t*)alloc((size_t)ROWS * CC * 2);

  // 1. weight fake-quant -> fp16 (both weights, one launch)
  k_qdq_w<<<(C3 * NG + CC * NG) / 256, 256, 0, stream>>>(w1, w2, w116, w216);
  // 2. LN + activation fake-quant -> fp16
  k_qh<<<(ROWS * NG) / 256, 256, 0, stream>>>(qx, sx, mean, rstd, lnw, h16);
  // 3. qkv = h @ w1^T  (fp16 MFMA, fp16 out)
  k_gemm16<half_t><<<dim3(C3 / 128, ROWS / 128), 256, 0, stream>>>(h16, w116, qkv16, C3);
  // 4. causal SDPA (fp16 MFMA flash, paired q-tiles, fused y fake-quant)
  k_attn16<<<dim3(BB * NH, 16), 256, 0, stream>>>(qkv16, y16);
  // 5. proj = y @ w2^T  (fp16 MFMA, fp16 out)
  k_gemm16<half_t><<<dim3(CC / 128, ROWS / 128), 256, 0, stream>>>(y16, w216, proj, CC);
  // 6. residual + stats + output quant
  k_final<<<ROWS, 256, 0, stream>>>(x, proj, o_fpx, o_qo, o_so, o_mean, o_rstd);
}

// Round 6
// 130.649 us; speedup vs baseline: 11.0771x; 1.0154x over previous
//
#include <hip/hip_runtime.h>
#include <stdint.h>

// Problem constants
#define BB 2
#define TT 2048
#define CC 1024
#define NH 16
#define HD 64
#define NG 32              // groups per C row (group size 32)
#define ROWS (BB*TT)       // 4096
#define C3 (3*CC)          // 3072

typedef _Float16 half_t;
typedef __attribute__((ext_vector_type(8))) _Float16 half8;
typedef __attribute__((ext_vector_type(2))) __fp16 fp16x2;
typedef __attribute__((ext_vector_type(4))) float f32x4;

#define GLDS16(g, l) __builtin_amdgcn_global_load_lds( \
    (__attribute__((address_space(1))) void*)(g), \
    (__attribute__((address_space(3))) void*)(l), 16, 0, 0)

#define LOG2E 1.44269504f
#define DEFER_THR 5.5451774f   /* 8 / log2(e) */

__device__ __forceinline__ uint32_t pk_h2(float a, float b) {
  union { fp16x2 h; uint32_t u; } cv;
  cv.h = __builtin_amdgcn_cvt_pkrtz(a, b);
  return cv.u;
}

// ---------------------------------------------------------------------------
// weight fake-quant fp32 -> fp16 dequantized values (both weights, one launch)
// ---------------------------------------------------------------------------
__global__ void k_qdq_w(const float* __restrict__ w1, const float* __restrict__ w2,
                        half_t* __restrict__ o1, half_t* __restrict__ o2) {
  int g = blockIdx.x * blockDim.x + threadIdx.x;
  const float* src; half_t* dst; int gl;
  if (g < C3 * NG) { src = w1; dst = o1; gl = g; }
  else             { src = w2; dst = o2; gl = g - C3 * NG; }
  const float4* p = reinterpret_cast<const float4*>(src + (size_t)gl * 32);
  float v[32]; float amax = 0.f;
  #pragma unroll
  for (int i = 0; i < 8; ++i) {
    float4 t = p[i];
    v[4*i] = t.x; v[4*i+1] = t.y; v[4*i+2] = t.z; v[4*i+3] = t.w;
    amax = fmaxf(amax, fmaxf(fmaxf(fabsf(t.x), fabsf(t.y)), fmaxf(fabsf(t.z), fabsf(t.w))));
  }
  float s = fmaxf(amax / 127.0f, 1e-8f);
  half_t* o = dst + (size_t)gl * 32;
  #pragma unroll
  for (int c = 0; c < 4; ++c) {
    half8 ov;
    #pragma unroll
    for (int jj = 0; jj < 8; ++jj) {
      float q = fminf(fmaxf(rintf(v[c*8+jj] / s), -127.f), 127.f);
      ov[jj] = (half_t)(q * s);
    }
    *reinterpret_cast<half8*>(o + c*8) = ov;
  }
}

// ---------------------------------------------------------------------------
// dequant(qx)+layernorm+fake-quant -> fp16 h. thread per group of 32.
// ---------------------------------------------------------------------------
__global__ void k_qh(const int* __restrict__ qx, const float* __restrict__ sx,
                     const float* __restrict__ mean, const float* __restrict__ rstd,
                     const float* __restrict__ lnw, half_t* __restrict__ h16) {
  int g = blockIdx.x * blockDim.x + threadIdx.x;
  if (g >= ROWS * NG) return;
  int row = g >> 5, grp = g & 31;
  float sxv = sx[g];
  float mu = mean[row], rs = rstd[row];
  const int4* qp = reinterpret_cast<const int4*>(qx + (size_t)row * CC + grp * 32);
  const float4* wp = reinterpret_cast<const float4*>(lnw + grp * 32);
  float v[32]; float amax = 0.f;
  #pragma unroll
  for (int i = 0; i < 8; ++i) {
    int4 qv = qp[i]; float4 wv = wp[i];
    float h0 = ((float)qv.x * sxv - mu) * rs * wv.x;
    float h1 = ((float)qv.y * sxv - mu) * rs * wv.y;
    float h2 = ((float)qv.z * sxv - mu) * rs * wv.z;
    float h3 = ((float)qv.w * sxv - mu) * rs * wv.w;
    v[4*i] = h0; v[4*i+1] = h1; v[4*i+2] = h2; v[4*i+3] = h3;
    amax = fmaxf(amax, fmaxf(fmaxf(fabsf(h0), fabsf(h1)), fmaxf(fabsf(h2), fabsf(h3))));
  }
  float s = fmaxf(amax / 127.0f, 1e-8f);
  half_t* o = h16 + (size_t)row * CC + grp * 32;
  #pragma unroll
  for (int c = 0; c < 4; ++c) {
    half8 ov;
    #pragma unroll
    for (int jj = 0; jj < 8; ++jj) {
      float q = fminf(fmaxf(rintf(v[c*8+jj] / s), -127.f), 127.f);
      ov[jj] = (half_t)(q * s);
    }
    *reinterpret_cast<half8*>(o + c*8) = ov;
  }
}

// ---------------------------------------------------------------------------
// fp16 MFMA GEMM: Out[m][n] = sum_k A[m][k]*B[n][k], K=1024.
// 128x128 tile, 4 waves (2x2 of 64x64), BK=32, global_load_lds staging.
// ---------------------------------------------------------------------------
template<typename TO>
__global__ __launch_bounds__(256) void k_gemm16(const half_t* __restrict__ A,
                                                const half_t* __restrict__ B,
                                                TO* __restrict__ Out, int N) {
  __shared__ __align__(16) half_t As[128*32];
  __shared__ __align__(16) half_t Bs[128*32];
  const int tid = threadIdx.x;
  const int wave = tid >> 6, lane = tid & 63;
  const int l15 = lane & 15, lg = lane >> 4;
  const int m0 = blockIdx.y * 128, n0 = blockIdx.x * 128;
  const int wm = (wave >> 1) * 64, wn = (wave & 1) * 64;
  f32x4 acc[4][4];
  #pragma unroll
  for (int i = 0; i < 4; ++i)
    #pragma unroll
    for (int jj = 0; jj < 4; ++jj) acc[i][jj] = f32x4{0.f, 0.f, 0.f, 0.f};
  const int srow = lane >> 2;        // 0..15 within segment
  const int scol = (lane & 3) * 8;   // halves
  const int seg0 = wave * 2;
  for (int k0 = 0; k0 < 1024; k0 += 32) {
    #pragma unroll
    for (int s = 0; s < 2; ++s) {
      const int seg = seg0 + s;
      GLDS16(A + (size_t)(m0 + seg*16 + srow) * 1024 + k0 + scol, As + seg*512);
      GLDS16(B + (size_t)(n0 + seg*16 + srow) * 1024 + k0 + scol, Bs + seg*512);
    }
    __syncthreads();
    half8 af[4], bf[4];
    #pragma unroll
    for (int i = 0; i < 4; ++i) {
      af[i] = *reinterpret_cast<const half8*>(As + (wm + i*16 + l15)*32 + lg*8);
      bf[i] = *reinterpret_cast<const half8*>(Bs + (wn + i*16 + l15)*32 + lg*8);
    }
    #pragma unroll
    for (int mi = 0; mi < 4; ++mi)
      #pragma unroll
      for (int ni = 0; ni < 4; ++ni)
        acc[mi][ni] = __builtin_amdgcn_mfma_f32_16x16x32_f16(af[mi], bf[ni], acc[mi][ni], 0, 0, 0);
    __syncthreads();
  }
  const int crow = m0 + wm + lg * 4;
  const int ccol = n0 + wn + l15;
  #pragma unroll
  for (int mi = 0; mi < 4; ++mi)
    #pragma unroll
    for (int ni = 0; ni < 4; ++ni)
      #pragma unroll
      for (int r = 0; r < 4; ++r)
        Out[(size_t)(crow + mi*16 + r) * N + ccol + ni*16] = (TO)acc[mi][ni][r];
}

// ---------------------------------------------------------------------------
// MFMA flash attention, paired q-tiles {j, 31-j}, 512 threads / 8 waves:
// waves 0-3 compute tile A(=j), waves 4-7 tile B(=31-j) CONCURRENTLY.
// Per-SIMD balance: each SIMD hosts one A-wave + one B-wave -> 33 units.
// K/V staged once per kt for both tiles; V^T via v_perm; l via MFMA ones.
// ---------------------------------------------------------------------------
__global__ __launch_bounds__(512, 4) void k_attn16(const half_t* __restrict__ qkv,
                                                   half_t* __restrict__ y16) {
  __shared__ __align__(16) half_t Ks[64*72];
  __shared__ __align__(16) half_t Vt[64*72];   // XOR-swizzled [dim][key-pair]
  __shared__ __align__(16) half_t Ps[8][16*72];
  const int tid = threadIdx.x;
  const int wave = tid >> 6, lane = tid & 63;
  const int l15 = lane & 15, lg = lane >> 4;
  const int w4 = wave & 3;
  const int bh = blockIdx.x, b = bh >> 4, h = bh & 15;
  const int j = blockIdx.y;
  const int qtB = 31 - j;
  const int qt = (wave >> 2) ? qtB : j;    // this wave's q-tile

  // Q fragment, prescaled by 1/sqrt(hd)=0.125 (exact in fp16)
  const size_t row = (size_t)(b * TT + qt * 64 + w4 * 16 + l15);
  const half_t* qp = qkv + row * C3 + h * HD + lg * 8;
  const half8 q0 = *reinterpret_cast<const half8*>(qp)      * (half_t)0.125f;
  const half8 q1 = *reinterpret_cast<const half8*>(qp + 32) * (half_t)0.125f;

  float m = -3.0e38f;
  f32x4 yacc[4];
  f32x4 lacc = f32x4{0,0,0,0};
  #pragma unroll
  for (int n = 0; n < 4; ++n) yacc[n] = f32x4{0,0,0,0};

  // staging maps (512 threads)
  const int sj = tid >> 3, sc = (tid & 7) * 8;       // K: key sj, dims sc..sc+7
  const int vkp = tid >> 4, vd0 = (tid & 15) * 4;    // V: keys 2vkp,2vkp+1, dims vd0..+3
  const int vxor = ((vd0 >> 3) & 7) << 2;            // dword-index XOR (16B granular)
  half_t* pw = &Ps[wave][0];
  uint32_t* vt32 = reinterpret_cast<uint32_t*>(Vt);

  // precomputed V^T read dword offsets (loop-invariant)
  int vdw0[4], vdw1[4];
  #pragma unroll
  for (int n = 0; n < 4; ++n) {
    const int d = n*16 + l15;
    const int x = ((n*2 + (l15 >> 3)) & 7) << 2;
    vdw0[n] = (d*36 + lg*4) ^ x;
    vdw1[n] = (d*36 + 16 + lg*4) ^ x;
  }

  half8 ones8;
  #pragma unroll
  for (int i = 0; i < 8; ++i) ones8[i] = (half_t)1.0f;

  // K/V prefetch registers
  half8 k0r; uint2 u0r, u1r;
  const half_t* kvb = qkv + ((size_t)b * TT) * C3 + CC + h * HD;
  auto kload = [&](int kt) {
    const half_t* kp = kvb + (size_t)(kt*64 + sj) * C3 + sc;
    k0r = *reinterpret_cast<const half8*>(kp);
    const half_t* vp = kvb + (size_t)(kt*64 + vkp*2) * C3 + CC + vd0;
    u0r = *reinterpret_cast<const uint2*>(vp);
    u1r = *reinterpret_cast<const uint2*>(vp + C3);
  };

  kload(0);
  for (int kt = 0; kt <= qtB; ++kt) {
    __syncthreads();   // previous tile's LDS reads complete
    *reinterpret_cast<half8*>(Ks + sj*72 + sc) = k0r;
    vt32[((vd0+0)*36 + vkp) ^ vxor] = __builtin_amdgcn_perm(u1r.x, u0r.x, 0x05040100u);
    vt32[((vd0+1)*36 + vkp) ^ vxor] = __builtin_amdgcn_perm(u1r.x, u0r.x, 0x07060302u);
    vt32[((vd0+2)*36 + vkp) ^ vxor] = __builtin_amdgcn_perm(u1r.y, u0r.y, 0x05040100u);
    vt32[((vd0+3)*36 + vkp) ^ vxor] = __builtin_amdgcn_perm(u1r.y, u0r.y, 0x07060302u);
    __syncthreads();   // staging visible
    if (kt < qtB) kload(kt + 1);   // prefetch next tile under compute
    if (kt <= qt) {
      // ---- QK^T ----
      f32x4 sacc[4];
      __builtin_amdgcn_s_setprio(1);
      #pragma unroll
      for (int kg = 0; kg < 4; ++kg) {
        const half8 a0 = *reinterpret_cast<const half8*>(Ks + (kg*16 + l15)*72 + lg*8);
        const half8 a1 = *reinterpret_cast<const half8*>(Ks + (kg*16 + l15)*72 + lg*8 + 32);
        f32x4 t = f32x4{0,0,0,0};
        t = __builtin_amdgcn_mfma_f32_16x16x32_f16(a0, q0, t, 0, 0, 0);
        t = __builtin_amdgcn_mfma_f32_16x16x32_f16(a1, q1, t, 0, 0, 0);
        sacc[kg] = t;
      }
      __builtin_amdgcn_s_setprio(0);
      // ---- softmax ----
      float sv[16]; float tm = -3.0e38f;
      const bool diag = (kt == qt);
      #pragma unroll
      for (int kg = 0; kg < 4; ++kg)
        #pragma unroll
        for (int r = 0; r < 4; ++r) {
          float s = sacc[kg][r];
          if (diag && (kg*16 + lg*4 + r > w4*16 + l15)) s = -1e30f;
          sv[kg*4 + r] = s;
          tm = fmaxf(tm, s);
        }
      tm = fmaxf(tm, __shfl_xor(tm, 16));
      tm = fmaxf(tm, __shfl_xor(tm, 32));
      if (!__all(tm <= m + DEFER_THR)) {
        const float mn = fmaxf(m, tm);
        const float alpha = __builtin_amdgcn_exp2f((m - mn) * LOG2E);
        #pragma unroll
        for (int n = 0; n < 4; ++n) yacc[n] *= alpha;
        lacc *= alpha;
        m = mn;
      }
      const float nm = -m * LOG2E;
      #pragma unroll
      for (int i = 0; i < 16; ++i)
        sv[i] = __builtin_amdgcn_exp2f(fmaf(sv[i], LOG2E, nm));
      // P -> wave-private LDS (packed half2, uint2 stores)
      uint32_t* pd = reinterpret_cast<uint32_t*>(pw) + l15*36 + lg*2;
      #pragma unroll
      for (int kg = 0; kg < 4; ++kg) {
        uint2 pr;
        pr.x = pk_h2(sv[kg*4 + 0], sv[kg*4 + 1]);
        pr.y = pk_h2(sv[kg*4 + 2], sv[kg*4 + 3]);
        *reinterpret_cast<uint2*>(pd + kg*8) = pr;
      }
      __builtin_amdgcn_sched_barrier(0);
      const half8 pb0 = *reinterpret_cast<const half8*>(pw + l15*72 + lg*8);
      const half8 pb1 = *reinterpret_cast<const half8*>(pw + l15*72 + lg*8 + 32);
      // ---- PV + row-sum ----
      __builtin_amdgcn_s_setprio(1);
      #pragma unroll
      for (int n = 0; n < 4; ++n) {
        const half8 va0 = *reinterpret_cast<const half8*>(vt32 + vdw0[n]);
        const half8 va1 = *reinterpret_cast<const half8*>(vt32 + vdw1[n]);
        yacc[n] = __builtin_amdgcn_mfma_f32_16x16x32_f16(va0, pb0, yacc[n], 0, 0, 0);
        yacc[n] = __builtin_amdgcn_mfma_f32_16x16x32_f16(va1, pb1, yacc[n], 0, 0, 0);
      }
      lacc = __builtin_amdgcn_mfma_f32_16x16x32_f16(ones8, pb0, lacc, 0, 0, 0);
      lacc = __builtin_amdgcn_mfma_f32_16x16x32_f16(ones8, pb1, lacc, 0, 0, 0);
      __builtin_amdgcn_s_setprio(0);
    }
  }

  // epilogue: normalize + fused group-32 fake-quant, write fp16 qdq values
  const float inv = 1.0f / lacc[0];
  float v[16];
  #pragma unroll
  for (int n = 0; n < 4; ++n)
    #pragma unroll
    for (int r = 0; r < 4; ++r) v[n*4 + r] = yacc[n][r] * inv;
  half_t* yp = y16 + row * CC + h * HD;
  #pragma unroll
  for (int g = 0; g < 2; ++g) {
    float am = 0.f;
    #pragma unroll
    for (int t = 0; t < 8; ++t) am = fmaxf(am, fabsf(v[g*8 + t]));
    am = fmaxf(am, __shfl_xor(am, 16));
    am = fmaxf(am, __shfl_xor(am, 32));
    const float s = fmaxf(am / 127.0f, 1e-8f);
    const float qi = 1.0f / s;
    #pragma unroll
    for (int nn = 0; nn < 2; ++nn) {
      const int n = g*2 + nn;
      union { half_t h4[4]; uint64_t u; } pk;
      #pragma unroll
      for (int r = 0; r < 4; ++r) {
        float q = fminf(fmaxf(rintf(v[n*4 + r] * qi), -127.f), 127.f);
        pk.h4[r] = (half_t)(q * s);
      }
      *reinterpret_cast<uint64_t*>(yp + n*16 + lg*4) = pk.u;
    }
  }
}

// ---------------------------------------------------------------------------
// residual + stats + output quantization. block per row (1024 elems, 256 thr)
// ---------------------------------------------------------------------------
__global__ __launch_bounds__(256) void k_final(
    const float* __restrict__ x, const half_t* __restrict__ proj,
    float* __restrict__ out_fpx, float* __restrict__ out_qo, float* __restrict__ out_so,
    float* __restrict__ out_mean, float* __restrict__ out_rstd) {
  __shared__ float red[16];
  int row = blockIdx.x;
  int tid = threadIdx.x;
  size_t base = (size_t)row * CC + tid * 4;
  float4 xv = *reinterpret_cast<const float4*>(x + base);
  union { uint64_t u; half_t h[4]; } pp;
  pp.u = *reinterpret_cast<const uint64_t*>(proj + base);
  float4 f;
  f.x = xv.x + (float)pp.h[0]; f.y = xv.y + (float)pp.h[1];
  f.z = xv.z + (float)pp.h[2]; f.w = xv.w + (float)pp.h[3];
  *reinterpret_cast<float4*>(out_fpx + base) = f;
  float sum = f.x + f.y + f.z + f.w;
  float sq  = f.x*f.x + f.y*f.y + f.z*f.z + f.w*f.w;
  #pragma unroll
  for (int off = 1; off < 64; off <<= 1) {
    sum += __shfl_xor(sum, off);
    sq  += __shfl_xor(sq, off);
  }
  int wid = tid >> 6, lane = tid & 63;
  if (lane == 0) { red[wid] = sum; red[8 + wid] = sq; }
  __syncthreads();
  if (tid == 0) {
    float s4 = red[0] + red[1] + red[2] + red[3];
    float q4 = red[8] + red[9] + red[10] + red[11];
    float mu = s4 * (1.0f / CC);
    float var = q4 * (1.0f / CC) - mu * mu;
    out_mean[row] = mu;
    out_rstd[row] = 1.0f / sqrtf(var + 1e-5f);
  }
  float amax = fmaxf(fmaxf(fabsf(f.x), fabsf(f.y)), fmaxf(fabsf(f.z), fabsf(f.w)));
  #pragma unroll
  for (int off = 1; off < 8; off <<= 1) amax = fmaxf(amax, __shfl_xor(amax, off, 8));
  float s = fmaxf(amax / 127.0f, 1e-8f);
  int g = tid >> 3, li = tid & 7;
  if (li == 0) out_so[row * NG + g] = s;
  float4 qo;
  qo.x = fminf(fmaxf(rintf(f.x / s), -127.f), 127.f);
  qo.y = fminf(fmaxf(rintf(f.y / s), -127.f), 127.f);
  qo.z = fminf(fmaxf(rintf(f.z / s), -127.f), 127.f);
  qo.w = fminf(fmaxf(rintf(f.w / s), -127.f), 127.f);
  *reinterpret_cast<float4*>(out_qo + base) = qo;
}

// ---------------------------------------------------------------------------
extern "C" void kernel_launch(void* const* d_in, const int* in_sizes, int n_in,
                              void* d_out, int out_size, void* d_ws, size_t ws_size,
                              hipStream_t stream) {
  const float* x    = (const float*)d_in[0];
  const int*   qx   = (const int*)d_in[1];
  const float* sx   = (const float*)d_in[2];
  const float* mean = (const float*)d_in[3];
  const float* rstd = (const float*)d_in[4];
  const float* lnw  = (const float*)d_in[5];
  const float* w1   = (const float*)d_in[6];
  const float* w2   = (const float*)d_in[7];

  float* out = (float*)d_out;
  float* o_fpx  = out;
  float* o_qo   = o_fpx + (size_t)ROWS * CC;
  float* o_so   = o_qo  + (size_t)ROWS * CC;
  float* o_mean = o_so  + (size_t)ROWS * NG;
  float* o_rstd = o_mean + ROWS;

  size_t off = 0;
  char* wsb = (char*)d_ws;
  auto alloc = [&](size_t bytes) -> void* {
    void* p = wsb + off;
    off += (bytes + 255) & ~(size_t)255;
    return p;
  };
  half_t* h16   = (half_t*)alloc((size_t)ROWS * CC * 2);
  half_t* w116  = (half_t*)alloc((size_t)C3 * CC * 2);
  half_t* w216  = (half_t*)alloc((size_t)CC * CC * 2);
  half_t* qkv16 = (half_t*)alloc((size_t)ROWS * C3 * 2);
  half_t* y16   = (half_t*)alloc((size_t)ROWS * CC * 2);
  half_t* proj  = (half_t*)alloc((size_t)ROWS * CC * 2);

  // 1. weight fake-quant -> fp16 (both weights, one launch)
  k_qdq_w<<<(C3 * NG + CC * NG) / 256, 256, 0, stream>>>(w1, w2, w116, w216);
  // 2. LN + activation fake-quant -> fp16
  k_qh<<<(ROWS * NG) / 256, 256, 0, stream>>>(qx, sx, mean, rstd, lnw, h16);
  // 3. qkv = h @ w1^T  (fp16 MFMA, fp16 out)
  k_gemm16<half_t><<<dim3(C3 / 128, ROWS / 128), 256, 0, stream>>>(h16, w116, qkv16, C3);
  // 4. causal SDPA (fp16 MFMA flash, concurrent paired q-tiles, fused y fake-quant)
  k_attn16<<<dim3(BB * NH, 16), 512, 0, stream>>>(qkv16, y16);
  // 5. proj = y @ w2^T  (fp16 MFMA, fp16 out)
  k_gemm16<half_t><<<dim3(CC / 128, ROWS / 128), 256, 0, stream>>>(y16, w216, proj, CC);
  // 6. residual + stats + output quant
  k_final<<<ROWS, 256, 0, stream>>>(x, proj, o_fpx, o_qo, o_so, o_mean, o_rstd);
}